// Round 10
// baseline (615.854 us; speedup 1.0000x reference)
//
#include <hip/hip_runtime.h>

#define N_NODES 100000
#define E_EDGES 300000
#define N_GRAPHS 2048

typedef float  floatx4 __attribute__((ext_vector_type(4)));
typedef short  shortx8 __attribute__((ext_vector_type(8)));

__device__ __forceinline__ float bf2f(unsigned short u) {
  return __uint_as_float(((unsigned int)u) << 16);
}
__device__ __forceinline__ unsigned short f2bf(float f) {
  unsigned int u = __float_as_uint(f);
  u += 0x7FFFu + ((u >> 16) & 1u);
  return (unsigned short)(u >> 16);
}

// async global->LDS, 16B per lane; lds base wave-uniform, dst = base+lane*16 (m104)
__device__ __forceinline__ void cp16(const void* g, void* l) {
  __builtin_amdgcn_global_load_lds(
      (const __attribute__((address_space(1))) unsigned int*)g,
      (__attribute__((address_space(3))) unsigned int*)l, 16, 0, 0);
}

// ---- prep kernel: all independent prologue work in ONE dispatch -------------
struct PrepArgs {
  const float* W[4];
  unsigned short* Wt[4];
  int K[4];
  int N[4];
  const float* We;
  const float* be;
  const float* W1_0;
  unsigned short* WfT;
  const float* W2_2;
  const float* b2_2;
  const float* wtask;
  float* w2v;
  float* c2;
  float* nodedot;   // points at cursor (int*) -- 0.0f bits == int 0
  float* out;
  const float* b_task;
};

__global__ __launch_bounds__(256)
void prep_kernel(PrepArgs a) {
  const int blk = blockIdx.x;
  if (blk < 320) {
    int z, b;
    if (blk < 64)       { z = 0; b = blk; }
    else if (blk < 128) { z = 1; b = blk - 64; }
    else if (blk < 192) { z = 2; b = blk - 128; }
    else                { z = 3; b = blk - 192; }
    const int K = a.K[z], N = a.N[z];
    const int nt = N / 32;
    const int kb = (b / nt) * 32, nb = (b % nt) * 32;
    __shared__ unsigned short tile[32][33];
    const float* W = a.W[z];
    unsigned short* Wt = a.Wt[z];
    const int tx = threadIdx.x & 31, ty = threadIdx.x >> 5;
    for (int r = ty; r < 32; r += 8)
      tile[r][tx] = f2bf(W[(size_t)(kb + r) * N + nb + tx]);
    __syncthreads();
    for (int r = ty; r < 32; r += 8)
      Wt[(size_t)(nb + r) * K + kb + tx] = tile[tx][r];
  } else if (blk < 361) {
    const int k = blk - 320;  // 0..40
    const int n = threadIdx.x;
    if (k < 40) {
      float s = 0.f;
      for (int j = 0; j < 128; j++) s = fmaf(a.We[k * 128 + j], a.W1_0[(size_t)j * 256 + n], s);
      a.WfT[n * 64 + k] = f2bf(s);
    } else {
      float s = 0.f;
      for (int j = 0; j < 128; j++) s = fmaf(a.be[j], a.W1_0[(size_t)j * 256 + n], s);
      a.WfT[n * 64 + 40] = f2bf(s);
      for (int kk = 41; kk < 64; kk++) a.WfT[n * 64 + kk] = 0;
    }
  } else if (blk < 490) {
    const int p = blk - 361;  // 0..128
    const int lane = threadIdx.x & 63;
    const int wave = threadIdx.x >> 6;
    if (p < 128) {
      const int k = p * 4 + wave;
      const float* row = a.W2_2 + (size_t)k * 512 + lane * 8;
      float4 a0 = *(const float4*)(row);
      float4 a1 = *(const float4*)(row + 4);
      float4 w0 = *(const float4*)(a.wtask + lane * 8);
      float4 w1 = *(const float4*)(a.wtask + lane * 8 + 4);
      float s = a0.x * w0.x + a0.y * w0.y + a0.z * w0.z + a0.w * w0.w +
                a1.x * w1.x + a1.y * w1.y + a1.z * w1.z + a1.w * w1.w;
#pragma unroll
      for (int off = 32; off > 0; off >>= 1) s += __shfl_down(s, off);
      if (lane == 0) a.w2v[k] = s;
    } else if (wave == 0) {
      float4 a0 = *(const float4*)(a.b2_2 + lane * 8);
      float4 a1 = *(const float4*)(a.b2_2 + lane * 8 + 4);
      float4 w0 = *(const float4*)(a.wtask + lane * 8);
      float4 w1 = *(const float4*)(a.wtask + lane * 8 + 4);
      float s = a0.x * w0.x + a0.y * w0.y + a0.z * w0.z + a0.w * w0.w +
                a1.x * w1.x + a1.y * w1.y + a1.z * w1.z + a1.w * w1.w;
#pragma unroll
      for (int off = 32; off > 0; off >>= 1) s += __shfl_down(s, off);
      if (lane == 0) *a.c2 = s;
    }
  } else if (blk < 881) {
    int i = (blk - 490) * 256 + threadIdx.x;
    if (i < N_NODES) a.nodedot[i] = 0.f;  // zeroes cursor (int 0 bits)
  } else {
    int g = (blk - 881) * 256 + threadIdx.x;
    if (g < N_GRAPHS) a.out[g] = a.b_task[0];
  }
}

// ---------------- CSR build: histogram, scan, fill ---------------------------
__global__ __launch_bounds__(256)
void hist_kernel(const int* __restrict__ ei, int* __restrict__ deg) {
  int e = blockIdx.x * 256 + threadIdx.x;
  if (e < E_EDGES) atomicAdd(&deg[ei[E_EDGES + e]], 1);
}

__global__ __launch_bounds__(256)
void scan_blk_kernel(const int* __restrict__ in, int* __restrict__ out,
                     int* __restrict__ blk_sums, int n_in, int n_out) {
  __shared__ int sm[256];
  const int t = threadIdx.x;
  const int base = blockIdx.x * 1024 + t * 4;
  int d0 = (base + 0 < n_in) ? in[base + 0] : 0;
  int d1 = (base + 1 < n_in) ? in[base + 1] : 0;
  int d2 = (base + 2 < n_in) ? in[base + 2] : 0;
  int d3 = (base + 3 < n_in) ? in[base + 3] : 0;
  int s = d0 + d1 + d2 + d3;
  sm[t] = s;
  __syncthreads();
  for (int off = 1; off < 256; off <<= 1) {
    int v = (t >= off) ? sm[t - off] : 0;
    __syncthreads();
    sm[t] += v;
    __syncthreads();
  }
  int excl = sm[t] - s;
  if (base + 0 < n_out) out[base + 0] = excl;
  if (base + 1 < n_out) out[base + 1] = excl + d0;
  if (base + 2 < n_out) out[base + 2] = excl + d0 + d1;
  if (base + 3 < n_out) out[base + 3] = excl + d0 + d1 + d2;
  if (t == 255 && blk_sums) blk_sums[blockIdx.x] = sm[255];
}

__global__ __launch_bounds__(256)
void scan_fix_kernel(int* __restrict__ row_ptr, const int* __restrict__ blk_off,
                     int* __restrict__ cursor) {
  int i = blockIdx.x * 256 + threadIdx.x;
  if (i <= N_NODES) {
    int v = row_ptr[i] + blk_off[i >> 10];
    row_ptr[i] = v;
    if (i < N_NODES) cursor[i] = v;
  }
}

__global__ __launch_bounds__(256)
void fill_kernel(const int* __restrict__ ei, int* __restrict__ cursor,
                 int* __restrict__ csr_src) {
  int e = blockIdx.x * 256 + threadIdx.x;
  if (e < E_EDGES) {
    int d = ei[E_EDGES + e];
    int slot = atomicAdd(&cursor[d], 1);
    csr_src[slot] = ei[e];
  }
}

// ---- gatherx: G[n,64] = bf16([(1+eps)X_n + sum X_src | f_n | 0...]) ---------
__global__ __launch_bounds__(256)
void gatherx_kernel(const float* __restrict__ X, unsigned short* __restrict__ G,
                    const int* __restrict__ row_ptr, const int* __restrict__ csr,
                    const float* __restrict__ eps) {
  const int node = blockIdx.x * 4 + (threadIdx.x >> 6);
  const int lane = threadIdx.x & 63;
  const float sc = 1.0f + eps[0];
  const int e0 = row_ptr[node];
  const int e1 = row_ptr[node + 1];
  float acc = 0.f;
  if (lane < 40) {
    acc = sc * X[(size_t)node * 40 + lane];
    int e = e0;
    for (; e + 4 <= e1; e += 4) {
      int s0 = csr[e], s1 = csr[e + 1], s2 = csr[e + 2], s3 = csr[e + 3];
      float a0 = X[(size_t)s0 * 40 + lane];
      float a1 = X[(size_t)s1 * 40 + lane];
      float a2 = X[(size_t)s2 * 40 + lane];
      float a3 = X[(size_t)s3 * 40 + lane];
      acc += (a0 + a1) + (a2 + a3);
    }
    for (; e < e1; e++)
      acc += X[(size_t)csr[e] * 40 + lane];
  } else if (lane == 40) {
    acc = sc + (float)(e1 - e0);
  }
  G[(size_t)node * 64 + lane] = f2bf(acc);
}

// ------- gather (D=256): Z[d] = bf16((1+eps)*H[d] + sum H[src]) --------------
// R25 paired-uint4 form (passed).
__global__ __launch_bounds__(256)
void gather_kernel(const unsigned short* __restrict__ H, unsigned short* __restrict__ Z,
                   const int* __restrict__ row_ptr, const int* __restrict__ csr,
                   const float* __restrict__ eps, int l) {
  const int node = blockIdx.x * 4 + (threadIdx.x >> 6);
  const int lane = threadIdx.x & 63;
  const int half = lane >> 5;   // 0: lanes 0-31, 1: lanes 32-63
  const int hl = lane & 31;     // dim-chunk within row (8 bf16 each)
  const float sc = 1.0f + eps[l];
  float acc[8];
#pragma unroll
  for (int k = 0; k < 8; k++) acc[k] = 0.f;

  if (half == 0) {
    uint4 v = *(const uint4*)(H + (size_t)node * 256 + hl * 8);
    acc[0] = sc * bf2f((unsigned short)(v.x & 0xFFFF));
    acc[1] = sc * bf2f((unsigned short)(v.x >> 16));
    acc[2] = sc * bf2f((unsigned short)(v.y & 0xFFFF));
    acc[3] = sc * bf2f((unsigned short)(v.y >> 16));
    acc[4] = sc * bf2f((unsigned short)(v.z & 0xFFFF));
    acc[5] = sc * bf2f((unsigned short)(v.z >> 16));
    acc[6] = sc * bf2f((unsigned short)(v.w & 0xFFFF));
    acc[7] = sc * bf2f((unsigned short)(v.w >> 16));
  }

  const int e0 = row_ptr[node];
  const int e1 = row_ptr[node + 1];
  int e = e0;
  for (; e + 2 <= e1; e += 2) {
    int s = csr[e + half];
    uint4 v = *(const uint4*)(H + (size_t)s * 256 + hl * 8);
    acc[0] += bf2f((unsigned short)(v.x & 0xFFFF));
    acc[1] += bf2f((unsigned short)(v.x >> 16));
    acc[2] += bf2f((unsigned short)(v.y & 0xFFFF));
    acc[3] += bf2f((unsigned short)(v.y >> 16));
    acc[4] += bf2f((unsigned short)(v.z & 0xFFFF));
    acc[5] += bf2f((unsigned short)(v.z >> 16));
    acc[6] += bf2f((unsigned short)(v.w & 0xFFFF));
    acc[7] += bf2f((unsigned short)(v.w >> 16));
  }
  if (e < e1 && half == 0) {  // odd-degree tail
    int s = csr[e];
    uint4 v = *(const uint4*)(H + (size_t)s * 256 + hl * 8);
    acc[0] += bf2f((unsigned short)(v.x & 0xFFFF));
    acc[1] += bf2f((unsigned short)(v.x >> 16));
    acc[2] += bf2f((unsigned short)(v.y & 0xFFFF));
    acc[3] += bf2f((unsigned short)(v.y >> 16));
    acc[4] += bf2f((unsigned short)(v.z & 0xFFFF));
    acc[5] += bf2f((unsigned short)(v.z >> 16));
    acc[6] += bf2f((unsigned short)(v.w & 0xFFFF));
    acc[7] += bf2f((unsigned short)(v.w >> 16));
  }

#pragma unroll
  for (int k = 0; k < 8; k++) acc[k] += __shfl_down(acc[k], 32);

  if (half == 0) {
    unsigned short z[8];
#pragma unroll
    for (int k = 0; k < 8; k++) z[k] = f2bf(acc[k]);
    *(uint4*)(Z + (size_t)node * 256 + hl * 8) = *(const uint4*)z;
  }
}

// ============================================================================
// R26: fused MLP, single-Bs + REGISTER prefetch (T14 issue-early/write-late)
// -> LDS 64->48 KB -> 3 blocks/CU (12 waves, 3/SIMD, +50% latency cover).
// R25 post-mortem: 61us @ MfmaUtil 16.6%, Occ 17% -- per SIMD only 2 waves:
// MFMA cover 160cyc < panel L2 latency ~250cyc -> exposed stall per barrier.
// Per flattened step s: {compute s from Bs; syncA (drains rg loads, covered
// by compute); ds_write rg->Bs (panel s+1); syncB; global_load panel s+2->rg}.
// All waitcnts compiler-managed (no hand vmcnt -- R23/R24 lesson). One-time
// T-rewrite sits between A and B of step NT1-1. Panel slot of thread =
// (p*256+tid)*8 shorts (same layout cp16 produced).
// ============================================================================
template <int K1>
__global__ __launch_bounds__(256, 3)
void fused_mlp_kernel(const unsigned short* __restrict__ A,    // [M][K1]
                      const unsigned short* __restrict__ W1t,  // [256][K1]
                      const float* __restrict__ b1,            // [256]
                      const unsigned short* __restrict__ W2t,  // [256][256]
                      const float* __restrict__ b2,            // [256]
                      unsigned short* __restrict__ H,          // [M][256]
                      int M) {
  constexpr int ACH = K1 / 8;           // 16B chunks per A row (8 or 32)
  constexpr int ZP = (64 * ACH) / 256;  // cp16 issues/thread for Z (2 or 8)
  constexpr int NT1 = K1 / 32;          // phase-1 K-steps (2 or 8)
  constexpr int S = NT1 + 8;            // flattened K-steps (W1 then W2)

  __shared__ unsigned short Bs[256 * 32];  // 16 KB single panel
  __shared__ unsigned short Ts[64 * 256];  // 32 KB (Z then T then H-stage)

  const int m0 = blockIdx.x * 64;
  const int tid = threadIdx.x;
  const int lane = tid & 63;
  const int wave = tid >> 6;
  const int fr = lane & 15;
  const int fq = lane >> 4;
  const int wn = wave * 64;

  // ---- stage Z once into Ts (per-lane pre-swizzled global source) ----
#pragma unroll
  for (int p = 0; p < ZP; p++) {
    int slot = p * 256 + tid;
    int row = slot / ACH;
    int cs = slot % ACH;
    int cg = cs ^ (row & 7);
    int grow = m0 + row;
    if (grow >= M) grow = M - 1;
    cp16(A + (size_t)grow * K1 + cg * 8, Ts + (size_t)(p * 256 + wn) * 8);
  }

  // ---- B staging source pointers (pre-swizzled, R19-verified) ----
  const int bn_ = tid >> 2;
  const int bc_ = tid & 3;
  const unsigned short* srcW1[4];
  const unsigned short* srcW2[4];
#pragma unroll
  for (int p = 0; p < 4; p++) {
    int n = p * 64 + bn_;
    int sw = (bc_ ^ ((n >> 1) & 3)) << 3;
    srcW1[p] = W1t + (size_t)n * K1 + sw;
    srcW2[p] = W2t + (size_t)n * 256 + sw;
  }
#define PSRC(s, p) ((s) < NT1 ? srcW1[p] + (s) * 32 : srcW2[p] + ((s) - NT1) * 32)

  // ---- B-frag LDS offsets (constant across K-steps) ----
  int offB[4];
#pragma unroll
  for (int j = 0; j < 4; j++) {
    int n = wn + j * 16 + fr;
    offB[j] = n * 32 + ((fq ^ ((n >> 1) & 3)) << 3);
  }

  // ---- prologue: panel 0 via cp16; panel 1 into rg ----
#pragma unroll
  for (int p = 0; p < 4; p++)
    cp16(PSRC(0, p), &Bs[(size_t)(p * 256 + wn) * 8]);
  uint4 rg[4];
#pragma unroll
  for (int p = 0; p < 4; p++) rg[p] = *(const uint4*)PSRC(1, p);

  floatx4 acc[4][4];
#pragma unroll
  for (int i = 0; i < 4; i++)
#pragma unroll
    for (int j = 0; j < 4; j++) acc[i][j] = (floatx4){0.f, 0.f, 0.f, 0.f};

  __syncthreads();  // Z + panel0 staged; panel-1 rg loads drained (one-time)

#pragma unroll
  for (int s = 0; s < S; s++) {
    // ---- compute panel s ----
    shortx8 af[4], bv[4];
    const int str = (s < NT1) ? K1 : 256;
    const int kc = ((s < NT1) ? s : s - NT1) * 4;
#pragma unroll
    for (int i = 0; i < 4; i++) {
      int row = i * 16 + fr;
      af[i] = *(const shortx8*)&Ts[row * str + (((kc + fq) ^ (fr & 7)) << 3)];
    }
#pragma unroll
    for (int j = 0; j < 4; j++) bv[j] = *(const shortx8*)&Bs[offB[j]];
#pragma unroll
    for (int i = 0; i < 4; i++)
#pragma unroll
      for (int j = 0; j < 4; j++)
        acc[i][j] = __builtin_amdgcn_mfma_f32_16x16x32_bf16(af[i], bv[j], acc[i][j], 0, 0, 0);

    __syncthreads();  // A: all Bs (and phase-boundary Ts) reads complete;
                      //    drains rg loads issued last step (covered)

    if (s == NT1 - 1) {
      // one-time transition: T = relu(acc + b1) overwrites Ts; acc reset
#pragma unroll
      for (int j = 0; j < 4; j++) {
        int col = wn + j * 16 + fr;
        float bb = b1[col];
        int cgc = col >> 3, c7 = col & 7;
#pragma unroll
        for (int i = 0; i < 4; i++)
#pragma unroll
          for (int r = 0; r < 4; r++) {
            int row = i * 16 + fq * 4 + r;
            float v = fmaxf(acc[i][j][r] + bb, 0.f);
            Ts[row * 256 + (((cgc ^ (row & 7)) << 3) | c7)] = f2bf(v);
            acc[i][j][r] = 0.f;
          }
      }
    }

    if (s + 1 < S) {  // write panel s+1 from rg into Bs
#pragma unroll
      for (int p = 0; p < 4; p++)
        *(uint4*)&Bs[(size_t)(p * 256 + tid) * 8] = rg[p];
    }
    __syncthreads();  // B: panel s+1 (and T at transition) visible

    if (s + 2 < S) {  // issue panel s+2 loads; cover = compute s+1
#pragma unroll
      for (int p = 0; p < 4; p++) rg[p] = *(const uint4*)PSRC(s + 2, p);
    }
  }
#undef PSRC

  // ---- epilogue: H = relu(acc + b2), staged via Ts for coalesced stores ----
  // (last loop barrier A guarantees all Ts reads done)
#pragma unroll
  for (int j = 0; j < 4; j++) {
    int col = wn + j * 16 + fr;
    float bb = b2[col];
    int cgc = col >> 3, c7 = col & 7;
#pragma unroll
    for (int i = 0; i < 4; i++)
#pragma unroll
      for (int r = 0; r < 4; r++) {
        int row = i * 16 + fq * 4 + r;
        float v = fmaxf(acc[i][j][r] + bb, 0.f);
        Ts[row * 256 + (((cgc ^ (row & 7)) << 3) | c7)] = f2bf(v);
      }
  }
  __syncthreads();
  const int r2 = tid >> 5;    // 0..7
  const int cg2 = tid & 31;   // output 16B chunk
#pragma unroll
  for (int p = 0; p < 8; p++) {
    int row = p * 8 + r2;
    int grow = m0 + row;
    if (grow < M) {
      uint4 v = *(const uint4*)&Ts[row * 256 + ((cg2 ^ (row & 7)) << 3)];
      *(uint4*)&H[(size_t)grow * 256 + cg2 * 8] = v;
    }
  }
}

// ============================================================================
// R26: fused layer-2 + task-dot, same single-Bs + register-prefetch pipeline.
// 16 flattened K-steps; pd-fold (register-only) after compute at s&7==7.
// Per-wave partials -> nodedot4[wave][row] via PLAIN stores (R22, kept).
// ============================================================================
__global__ __launch_bounds__(256, 3)
void fused_dot_kernel(const unsigned short* __restrict__ A,    // Z [M][256]
                      const unsigned short* __restrict__ W1t,  // [512][256]
                      const float* __restrict__ b1,            // [512]
                      const float* __restrict__ w2v,           // [512]
                      float* __restrict__ nodedot4, int M) {
  __shared__ unsigned short Bs[256 * 32];  // 16 KB single panel
  __shared__ unsigned short Ts[64 * 256];  // 32 KB (Z)

  const int m0 = blockIdx.x * 64;
  const int tid = threadIdx.x;
  const int lane = tid & 63;
  const int wave = tid >> 6;
  const int fr = lane & 15;
  const int fq = lane >> 4;
  const int wn = wave * 64;

#pragma unroll
  for (int p = 0; p < 8; p++) {
    int slot = p * 256 + tid;
    int row = slot >> 5;
    int cs = slot & 31;
    int cg = cs ^ (row & 7);
    int grow = m0 + row;
    if (grow >= M) grow = M - 1;
    cp16(A + (size_t)grow * 256 + cg * 8, Ts + (size_t)(p * 256 + wn) * 8);
  }

  const int bn_ = tid >> 2;
  const int bc_ = tid & 3;
  const unsigned short* srcW[4];
#pragma unroll
  for (int p = 0; p < 4; p++) {
    int n = p * 64 + bn_;
    srcW[p] = W1t + (size_t)n * 256 + ((bc_ ^ ((n >> 1) & 3)) << 3);
  }
#define DSRC(s, p) (srcW[p] + (size_t)((s) >> 3) * 65536 + (size_t)((s) & 7) * 32)
  int offB[4];
#pragma unroll
  for (int j = 0; j < 4; j++) {
    int n = wn + j * 16 + fr;
    offB[j] = n * 32 + ((fq ^ ((n >> 1) & 3)) << 3);
  }

  // prologue: panel 0 via cp16; panel 1 into rg
#pragma unroll
  for (int p = 0; p < 4; p++)
    cp16(DSRC(0, p), &Bs[(size_t)(p * 256 + wn) * 8]);
  uint4 rg[4];
#pragma unroll
  for (int p = 0; p < 4; p++) rg[p] = *(const uint4*)DSRC(1, p);

  float pd[4][4];
#pragma unroll
  for (int i = 0; i < 4; i++)
#pragma unroll
    for (int r = 0; r < 4; r++) pd[i][r] = 0.f;

  floatx4 acc[4][4];
#pragma unroll
  for (int i = 0; i < 4; i++)
#pragma unroll
    for (int j = 0; j < 4; j++) acc[i][j] = (floatx4){0.f, 0.f, 0.f, 0.f};

  __syncthreads();  // Z + panel0 staged; panel-1 rg loads drained (one-time)

#pragma unroll
  for (int s = 0; s < 16; s++) {
    shortx8 af[4], bv[4];
    const int kc = (s & 7) * 4;
#pragma unroll
    for (int i = 0; i < 4; i++) {
      int row = i * 16 + fr;
      af[i] = *(const shortx8*)&Ts[row * 256 + (((kc + fq) ^ (fr & 7)) << 3)];
    }
#pragma unroll
    for (int j = 0; j < 4; j++) bv[j] = *(const shortx8*)&Bs[offB[j]];
#pragma unroll
    for (int i = 0; i < 4; i++)
#pragma unroll
      for (int j = 0; j < 4; j++)
        acc[i][j] = __builtin_amdgcn_mfma_f32_16x16x32_bf16(af[i], bv[j], acc[i][j], 0, 0, 0);

    if ((s & 7) == 7) {  // end of a 256-col half: fold into pd (register-only)
      const int nh = s >> 3;
#pragma unroll
      for (int j = 0; j < 4; j++) {
        int col = nh * 256 + wn + j * 16 + fr;
        float bb = b1[col];
        float wv = w2v[col];
#pragma unroll
        for (int i = 0; i < 4; i++)
#pragma unroll
          for (int r = 0; r < 4; r++) {
            pd[i][r] += fmaxf(acc[i][j][r] + bb, 0.f) * wv;
            acc[i][j][r] = 0.f;
          }
      }
    }

    __syncthreads();  // A: Bs reads done; drains rg loads (covered)
    if (s + 1 < 16) {
#pragma unroll
      for (int p = 0; p < 4; p++)
        *(uint4*)&Bs[(size_t)(p * 256 + tid) * 8] = rg[p];
    }
    __syncthreads();  // B: panel s+1 visible
    if (s + 2 < 16) {
#pragma unroll
      for (int p = 0; p < 4; p++) rg[p] = *(const uint4*)DSRC(s + 2, p);
    }
  }
#undef DSRC

#pragma unroll
  for (int i = 0; i < 4; i++)
#pragma unroll
    for (int r = 0; r < 4; r++) {
      float s = pd[i][r];
#pragma unroll
      for (int off = 1; off < 16; off <<= 1) s += __shfl_xor(s, off);
      if (fr == 0) {
        int row = m0 + i * 16 + fq * 4 + r;
        // plain store: plane `wave`, row owned by exactly this block
        if (row < M) nodedot4[(size_t)wave * N_NODES + row] = s;
      }
    }
}

// ---------------- readout ----------------------------------------------------
// R22 (kept): one thread per node; wave-level key-segmented inclusive scan
// (batch sorted) -> ~one atomicAdd per graph-run per wave.
__global__ __launch_bounds__(256)
void pool_kernel(const float* __restrict__ nodedot4, const int* __restrict__ batch,
                 float* __restrict__ out, const float* __restrict__ c2p) {
  const int i = blockIdx.x * 256 + threadIdx.x;
  if (i >= N_NODES) return;
  const int lane = threadIdx.x & 63;
  const float c2 = *c2p;
  float v = (nodedot4[i] + nodedot4[N_NODES + i]) +
            (nodedot4[2 * N_NODES + i] + nodedot4[3 * N_NODES + i]) + c2;
  const int g = batch[i];
  float s = v;
#pragma unroll
  for (int off = 1; off < 64; off <<= 1) {
    float u = __shfl_up(s, off);
    int gu = __shfl_up(g, off);
    if (lane >= off && gu == g) s += u;
  }
  bool last = (i == N_NODES - 1) || (batch[i + 1] != g) || (lane == 63);
  if (last) unsafeAtomicAdd(&out[g], s);
}

extern "C" void kernel_launch(void* const* d_in, const int* in_sizes, int n_in,
                              void* d_out, int out_size, void* d_ws, size_t ws_size,
                              hipStream_t stream) {
  const float* x       = (const float*)d_in[0];
  const int*   ei      = (const int*)d_in[1];
  const int*   batch   = (const int*)d_in[2];
  const float* W_embed = (const float*)d_in[3];
  const float* b_embed = (const float*)d_in[4];
  const float* eps     = (const float*)d_in[5];
  const float* W1[3] = {(const float*)d_in[6],  (const float*)d_in[10], (const float*)d_in[14]};
  const float* B1[3] = {(const float*)d_in[7],  (const float*)d_in[11], (const float*)d_in[15]};
  const float* W2[3] = {(const float*)d_in[8],  (const float*)d_in[12], (const float*)d_in[16]};
  const float* B2[3] = {(const float*)d_in[9],  (const float*)d_in[13], (const float*)d_in[17]};
  const float* W_task = (const float*)d_in[18];
  const float* b_task = (const float*)d_in[19];
  float* out = (float*)d_out;

  const size_t OFF_ND4 = 51200000;   // old RB region, free since R18: 4x100000 floats
  const size_t OFF_RZ  = 102400000;
  const size_t OFF_AUX = 153600000;
  if (ws_size < OFF_AUX + 4000000) return;
  unsigned short* RH = (unsigned short*)d_ws;
  float* nodedot4 = (float*)((char*)d_ws + OFF_ND4);
  unsigned short* RZ = (unsigned short*)((char*)d_ws + OFF_RZ);
  char* aux = (char*)d_ws + OFF_AUX;
  int* row_ptr  = (int*)(aux);               // 100001 ints
  int* cursor   = (int*)(aux + 400016);      // 100000 ints (also deg histogram)
  int* csr_src  = (int*)(aux + 800016);      // 300000 ints
  int* blk_sums = (int*)(aux + 2000016);     // 98 ints
  int* blk_off  = (int*)(aux + 2000416);     // 98 ints
  unsigned short* WT = (unsigned short*)(aux + 2400832);  // 360448 bf16
  float* w2v = (float*)(aux + 3200832);      // 512 floats
  float* c2  = (float*)(aux + 3202880);      // 1 float
  unsigned short* WfT    = WT;
  unsigned short* Wt2_0  = WT + 32768;
  unsigned short* Wt1_1  = WT + 98304;
  unsigned short* Wt2_1  = WT + 163840;
  unsigned short* Wt1_2  = WT + 229376;

  // ---- prep: all independent prologue work (1 dispatch; zeroes cursor) ----
  PrepArgs pa;
  pa.W[0] = W2[0]; pa.Wt[0] = Wt2_0; pa.K[0] = 256; pa.N[0] = 256;
  pa.W[1] = W1[1]; pa.Wt[1] = Wt1_1; pa.K[1] = 256; pa.N[1] = 256;
  pa.W[2] = W2[1]; pa.Wt[2] = Wt2_1; pa.K[2] = 256; pa.N[2] = 256;
  pa.W[3] = W1[2]; pa.Wt[3] = Wt1_2; pa.K[3] = 256; pa.N[3] = 512;
  pa.We = W_embed; pa.be = b_embed; pa.W1_0 = W1[0]; pa.WfT = WfT;
  pa.W2_2 = W2[2]; pa.b2_2 = B2[2]; pa.wtask = W_task; pa.w2v = w2v; pa.c2 = c2;
  pa.nodedot = (float*)cursor;  // zero cursor here (0.0f bits == 0)
  pa.out = out; pa.b_task = b_task;
  prep_kernel<<<889, 256, 0, stream>>>(pa);

  // ---- CSR build (zero_kernel folded into prep) ----
  hist_kernel<<<(E_EDGES + 255) / 256, 256, 0, stream>>>(ei, cursor);
  scan_blk_kernel<<<98, 256, 0, stream>>>(cursor, row_ptr, blk_sums, N_NODES, N_NODES + 1);
  scan_blk_kernel<<<1, 256, 0, stream>>>(blk_sums, blk_off, nullptr, 98, 98);
  scan_fix_kernel<<<(N_NODES + 256) / 256, 256, 0, stream>>>(row_ptr, blk_off, cursor);
  fill_kernel<<<(E_EDGES + 255) / 256, 256, 0, stream>>>(ei, cursor, csr_src);

  const int FB = (N_NODES + 63) / 64;  // 1563 fused blocks (64 rows each)

  // ---- layer 0 (folded embed): G -> H = relu(relu(G@WfT^T+b1)@W2_0+b2) ----
  gatherx_kernel<<<N_NODES / 4, 256, 0, stream>>>(x, RZ, row_ptr, csr_src, eps);
  fused_mlp_kernel<64><<<FB, 256, 0, stream>>>(RZ, WfT, B1[0], Wt2_0, B2[0], RH, N_NODES);

  // ---- layer 1 ----
  gather_kernel<<<N_NODES / 4, 256, 0, stream>>>(RH, RZ, row_ptr, csr_src, eps, 1);
  fused_mlp_kernel<256><<<FB, 256, 0, stream>>>(RZ, Wt1_1, B1[1], Wt2_1, B2[1], RH, N_NODES);

  // ---- layer 2: gather, then fused GEMM + task-dot ----
  gather_kernel<<<N_NODES / 4, 256, 0, stream>>>(RH, RZ, row_ptr, csr_src, eps, 2);
  fused_dot_kernel<<<FB, 256, 0, stream>>>(RZ, Wt1_2, B1[2], w2v, nodedot4, N_NODES);

  // ---- out[g] = b_task + sum_i (sum_w nodedot4[w][i] + c2) ----
  pool_kernel<<<(N_NODES + 255) / 256, 256, 0, stream>>>(nodedot4, batch, out, c2);
}

// Round 11
// 434.047 us; speedup vs baseline: 1.4189x; 1.4189x over previous
//
#include <hip/hip_runtime.h>

#define N_NODES 100000
#define E_EDGES 300000
#define N_GRAPHS 2048

typedef float  floatx4 __attribute__((ext_vector_type(4)));
typedef short  shortx8 __attribute__((ext_vector_type(8)));

__device__ __forceinline__ float bf2f(unsigned short u) {
  return __uint_as_float(((unsigned int)u) << 16);
}
__device__ __forceinline__ unsigned short f2bf(float f) {
  unsigned int u = __float_as_uint(f);
  u += 0x7FFFu + ((u >> 16) & 1u);
  return (unsigned short)(u >> 16);
}

// async global->LDS, 16B per lane; lds base wave-uniform, dst = base+lane*16 (m104)
__device__ __forceinline__ void cp16(const void* g, void* l) {
  __builtin_amdgcn_global_load_lds(
      (const __attribute__((address_space(1))) unsigned int*)g,
      (__attribute__((address_space(3))) unsigned int*)l, 16, 0, 0);
}

__device__ __forceinline__ void acc8(float* a, uint4 v) {
  a[0] += bf2f((unsigned short)(v.x & 0xFFFF));
  a[1] += bf2f((unsigned short)(v.x >> 16));
  a[2] += bf2f((unsigned short)(v.y & 0xFFFF));
  a[3] += bf2f((unsigned short)(v.y >> 16));
  a[4] += bf2f((unsigned short)(v.z & 0xFFFF));
  a[5] += bf2f((unsigned short)(v.z >> 16));
  a[6] += bf2f((unsigned short)(v.w & 0xFFFF));
  a[7] += bf2f((unsigned short)(v.w >> 16));
}

// ---- R27: fused gather-stage --------------------------------------------
// Builds Ts[row][256] = bf16((1+eps)*H[node] + sum_{nbr} H[nbr]) with the
// verified XOR swizzle (global chunk c -> LDS chunk c^(row&7)). Thread
// (row = tid>>5 + 8p, chunk = tid&31); f32 accumulate, dual accumulators
// for 2-deep load ILP. Replaces gather_kernel + cp16 Z-staging.
__device__ __forceinline__ void gather_stage(
    const unsigned short* __restrict__ H, const int* __restrict__ row_ptr,
    const int* __restrict__ csr, float sc, int m0, int M,
    unsigned short* Ts, int tid) {
  const int c = tid & 31;
  const int r0 = tid >> 5;
#pragma unroll
  for (int p = 0; p < 8; p++) {
    const int row = r0 + p * 8;
    int node = m0 + row;
    if (node >= M) node = M - 1;
    uint4 v = *(const uint4*)(H + (size_t)node * 256 + c * 8);
    float a0[8], a1[8];
    a0[0] = sc * bf2f((unsigned short)(v.x & 0xFFFF));
    a0[1] = sc * bf2f((unsigned short)(v.x >> 16));
    a0[2] = sc * bf2f((unsigned short)(v.y & 0xFFFF));
    a0[3] = sc * bf2f((unsigned short)(v.y >> 16));
    a0[4] = sc * bf2f((unsigned short)(v.z & 0xFFFF));
    a0[5] = sc * bf2f((unsigned short)(v.z >> 16));
    a0[6] = sc * bf2f((unsigned short)(v.w & 0xFFFF));
    a0[7] = sc * bf2f((unsigned short)(v.w >> 16));
#pragma unroll
    for (int k = 0; k < 8; k++) a1[k] = 0.f;
    const int e0 = row_ptr[node];
    const int e1 = row_ptr[node + 1];
    int e = e0;
    for (; e + 2 <= e1; e += 2) {
      int s0 = csr[e], s1 = csr[e + 1];
      uint4 u0 = *(const uint4*)(H + (size_t)s0 * 256 + c * 8);
      uint4 u1 = *(const uint4*)(H + (size_t)s1 * 256 + c * 8);
      acc8(a0, u0);
      acc8(a1, u1);
    }
    if (e < e1) {
      uint4 u0 = *(const uint4*)(H + (size_t)csr[e] * 256 + c * 8);
      acc8(a0, u0);
    }
    unsigned short z[8];
#pragma unroll
    for (int k = 0; k < 8; k++) z[k] = f2bf(a0[k] + a1[k]);
    *(uint4*)&Ts[row * 256 + ((c ^ (row & 7)) << 3)] = *(const uint4*)z;
  }
}

// ---- prep kernel: all independent prologue work in ONE dispatch -------------
struct PrepArgs {
  const float* W[4];
  unsigned short* Wt[4];
  int K[4];
  int N[4];
  const float* We;
  const float* be;
  const float* W1_0;
  unsigned short* WfT;
  const float* W2_2;
  const float* b2_2;
  const float* wtask;
  float* w2v;
  float* c2;
  float* nodedot;   // points at cursor (int*) -- 0.0f bits == int 0
  float* out;
  const float* b_task;
};

__global__ __launch_bounds__(256)
void prep_kernel(PrepArgs a) {
  const int blk = blockIdx.x;
  if (blk < 320) {
    int z, b;
    if (blk < 64)       { z = 0; b = blk; }
    else if (blk < 128) { z = 1; b = blk - 64; }
    else if (blk < 192) { z = 2; b = blk - 128; }
    else                { z = 3; b = blk - 192; }
    const int K = a.K[z], N = a.N[z];
    const int nt = N / 32;
    const int kb = (b / nt) * 32, nb = (b % nt) * 32;
    __shared__ unsigned short tile[32][33];
    const float* W = a.W[z];
    unsigned short* Wt = a.Wt[z];
    const int tx = threadIdx.x & 31, ty = threadIdx.x >> 5;
    for (int r = ty; r < 32; r += 8)
      tile[r][tx] = f2bf(W[(size_t)(kb + r) * N + nb + tx]);
    __syncthreads();
    for (int r = ty; r < 32; r += 8)
      Wt[(size_t)(nb + r) * K + kb + tx] = tile[tx][r];
  } else if (blk < 361) {
    const int k = blk - 320;  // 0..40
    const int n = threadIdx.x;
    if (k < 40) {
      float s = 0.f;
      for (int j = 0; j < 128; j++) s = fmaf(a.We[k * 128 + j], a.W1_0[(size_t)j * 256 + n], s);
      a.WfT[n * 64 + k] = f2bf(s);
    } else {
      float s = 0.f;
      for (int j = 0; j < 128; j++) s = fmaf(a.be[j], a.W1_0[(size_t)j * 256 + n], s);
      a.WfT[n * 64 + 40] = f2bf(s);
      for (int kk = 41; kk < 64; kk++) a.WfT[n * 64 + kk] = 0;
    }
  } else if (blk < 490) {
    const int p = blk - 361;  // 0..128
    const int lane = threadIdx.x & 63;
    const int wave = threadIdx.x >> 6;
    if (p < 128) {
      const int k = p * 4 + wave;
      const float* row = a.W2_2 + (size_t)k * 512 + lane * 8;
      float4 a0 = *(const float4*)(row);
      float4 a1 = *(const float4*)(row + 4);
      float4 w0 = *(const float4*)(a.wtask + lane * 8);
      float4 w1 = *(const float4*)(a.wtask + lane * 8 + 4);
      float s = a0.x * w0.x + a0.y * w0.y + a0.z * w0.z + a0.w * w0.w +
                a1.x * w1.x + a1.y * w1.y + a1.z * w1.z + a1.w * w1.w;
#pragma unroll
      for (int off = 32; off > 0; off >>= 1) s += __shfl_down(s, off);
      if (lane == 0) a.w2v[k] = s;
    } else if (wave == 0) {
      float4 a0 = *(const float4*)(a.b2_2 + lane * 8);
      float4 a1 = *(const float4*)(a.b2_2 + lane * 8 + 4);
      float4 w0 = *(const float4*)(a.wtask + lane * 8);
      float4 w1 = *(const float4*)(a.wtask + lane * 8 + 4);
      float s = a0.x * w0.x + a0.y * w0.y + a0.z * w0.z + a0.w * w0.w +
                a1.x * w1.x + a1.y * w1.y + a1.z * w1.z + a1.w * w1.w;
#pragma unroll
      for (int off = 32; off > 0; off >>= 1) s += __shfl_down(s, off);
      if (lane == 0) *a.c2 = s;
    }
  } else if (blk < 881) {
    int i = (blk - 490) * 256 + threadIdx.x;
    if (i < N_NODES) a.nodedot[i] = 0.f;  // zeroes cursor (int 0 bits)
  } else {
    int g = (blk - 881) * 256 + threadIdx.x;
    if (g < N_GRAPHS) a.out[g] = a.b_task[0];
  }
}

// ---------------- CSR build: histogram, scan, fill ---------------------------
__global__ __launch_bounds__(256)
void hist_kernel(const int* __restrict__ ei, int* __restrict__ deg) {
  int e = blockIdx.x * 256 + threadIdx.x;
  if (e < E_EDGES) atomicAdd(&deg[ei[E_EDGES + e]], 1);
}

__global__ __launch_bounds__(256)
void scan_blk_kernel(const int* __restrict__ in, int* __restrict__ out,
                     int* __restrict__ blk_sums, int n_in, int n_out) {
  __shared__ int sm[256];
  const int t = threadIdx.x;
  const int base = blockIdx.x * 1024 + t * 4;
  int d0 = (base + 0 < n_in) ? in[base + 0] : 0;
  int d1 = (base + 1 < n_in) ? in[base + 1] : 0;
  int d2 = (base + 2 < n_in) ? in[base + 2] : 0;
  int d3 = (base + 3 < n_in) ? in[base + 3] : 0;
  int s = d0 + d1 + d2 + d3;
  sm[t] = s;
  __syncthreads();
  for (int off = 1; off < 256; off <<= 1) {
    int v = (t >= off) ? sm[t - off] : 0;
    __syncthreads();
    sm[t] += v;
    __syncthreads();
  }
  int excl = sm[t] - s;
  if (base + 0 < n_out) out[base + 0] = excl;
  if (base + 1 < n_out) out[base + 1] = excl + d0;
  if (base + 2 < n_out) out[base + 2] = excl + d0 + d1;
  if (base + 3 < n_out) out[base + 3] = excl + d0 + d1 + d2;
  if (t == 255 && blk_sums) blk_sums[blockIdx.x] = sm[255];
}

__global__ __launch_bounds__(256)
void scan_fix_kernel(int* __restrict__ row_ptr, const int* __restrict__ blk_off,
                     int* __restrict__ cursor) {
  int i = blockIdx.x * 256 + threadIdx.x;
  if (i <= N_NODES) {
    int v = row_ptr[i] + blk_off[i >> 10];
    row_ptr[i] = v;
    if (i < N_NODES) cursor[i] = v;
  }
}

__global__ __launch_bounds__(256)
void fill_kernel(const int* __restrict__ ei, int* __restrict__ cursor,
                 int* __restrict__ csr_src) {
  int e = blockIdx.x * 256 + threadIdx.x;
  if (e < E_EDGES) {
    int d = ei[E_EDGES + e];
    int slot = atomicAdd(&cursor[d], 1);
    csr_src[slot] = ei[e];
  }
}

// ---- gatherx: G[n,64] = bf16([(1+eps)X_n + sum X_src | f_n | 0...]) ---------
__global__ __launch_bounds__(256)
void gatherx_kernel(const float* __restrict__ X, unsigned short* __restrict__ G,
                    const int* __restrict__ row_ptr, const int* __restrict__ csr,
                    const float* __restrict__ eps) {
  const int node = blockIdx.x * 4 + (threadIdx.x >> 6);
  const int lane = threadIdx.x & 63;
  const float sc = 1.0f + eps[0];
  const int e0 = row_ptr[node];
  const int e1 = row_ptr[node + 1];
  float acc = 0.f;
  if (lane < 40) {
    acc = sc * X[(size_t)node * 40 + lane];
    int e = e0;
    for (; e + 4 <= e1; e += 4) {
      int s0 = csr[e], s1 = csr[e + 1], s2 = csr[e + 2], s3 = csr[e + 3];
      float a0 = X[(size_t)s0 * 40 + lane];
      float a1 = X[(size_t)s1 * 40 + lane];
      float a2 = X[(size_t)s2 * 40 + lane];
      float a3 = X[(size_t)s3 * 40 + lane];
      acc += (a0 + a1) + (a2 + a3);
    }
    for (; e < e1; e++)
      acc += X[(size_t)csr[e] * 40 + lane];
  } else if (lane == 40) {
    acc = sc + (float)(e1 - e0);
  }
  G[(size_t)node * 64 + lane] = f2bf(acc);
}

// ============================================================================
// R22 (verbatim, last-good): fused per-layer MLP with minimum 2-phase pipeline.
// Used for layer 0 only (K1=64, input G from gatherx).
// ============================================================================
template <int K1>
__global__ __launch_bounds__(256, 2)
void fused_mlp_kernel(const unsigned short* __restrict__ A,    // [M][K1]
                      const unsigned short* __restrict__ W1t,  // [256][K1]
                      const float* __restrict__ b1,            // [256]
                      const unsigned short* __restrict__ W2t,  // [256][256]
                      const float* __restrict__ b2,            // [256]
                      unsigned short* __restrict__ H,          // [M][256]
                      int M) {
  constexpr int ACH = K1 / 8;           // 16B chunks per A row
  constexpr int ZP = (64 * ACH) / 256;  // cp16 issues/thread for Z
  constexpr int NT1 = K1 / 32;          // phase-1 K-steps

  __shared__ unsigned short Bs[2][256 * 32];  // 2 x 16 KB W-panel dbuf
  __shared__ unsigned short Ts[64 * 256];     // 32 KB (Z then T then H-stage)

  const int m0 = blockIdx.x * 64;
  const int tid = threadIdx.x;
  const int lane = tid & 63;
  const int wave = tid >> 6;
  const int fr = lane & 15;
  const int fq = lane >> 4;
  const int wn = wave * 64;

#pragma unroll
  for (int p = 0; p < ZP; p++) {
    int slot = p * 256 + tid;
    int row = slot / ACH;
    int cs = slot % ACH;
    int cg = cs ^ (row & 7);
    int grow = m0 + row;
    if (grow >= M) grow = M - 1;
    cp16(A + (size_t)grow * K1 + cg * 8, Ts + (size_t)(p * 256 + wn) * 8);
  }

  const int bn_ = tid >> 2;
  const int bc_ = tid & 3;
  const unsigned short* srcW1[4];
  const unsigned short* srcW2[4];
#pragma unroll
  for (int p = 0; p < 4; p++) {
    int n = p * 64 + bn_;
    int sw = (bc_ ^ ((n >> 1) & 3)) << 3;
    srcW1[p] = W1t + (size_t)n * K1 + sw;
    srcW2[p] = W2t + (size_t)n * 256 + sw;
  }

  int offB[4];
#pragma unroll
  for (int j = 0; j < 4; j++) {
    int n = wn + j * 16 + fr;
    offB[j] = n * 32 + ((fq ^ ((n >> 1) & 3)) << 3);
  }

#pragma unroll
  for (int p = 0; p < 4; p++)
    cp16(srcW1[p], &Bs[0][(size_t)(p * 256 + wn) * 8]);

  floatx4 acc[4][4];
#pragma unroll
  for (int i = 0; i < 4; i++)
#pragma unroll
    for (int j = 0; j < 4; j++) acc[i][j] = (floatx4){0.f, 0.f, 0.f, 0.f};

  __syncthreads();
  int buf = 0;

  for (int t = 0; t < NT1; t++) {
    if (t + 1 < NT1) {
#pragma unroll
      for (int p = 0; p < 4; p++)
        cp16(srcW1[p] + (t + 1) * 32, &Bs[buf ^ 1][(size_t)(p * 256 + wn) * 8]);
    } else {
#pragma unroll
      for (int p = 0; p < 4; p++)
        cp16(srcW2[p], &Bs[buf ^ 1][(size_t)(p * 256 + wn) * 8]);
    }
    shortx8 af[4], bv[4];
    const int kc = t * 4;
#pragma unroll
    for (int i = 0; i < 4; i++) {
      int row = i * 16 + fr;
      af[i] = *(const shortx8*)&Ts[row * K1 + (((kc + fq) ^ (fr & 7)) << 3)];
    }
#pragma unroll
    for (int j = 0; j < 4; j++) bv[j] = *(const shortx8*)&Bs[buf][offB[j]];
#pragma unroll
    for (int i = 0; i < 4; i++)
#pragma unroll
      for (int j = 0; j < 4; j++)
        acc[i][j] = __builtin_amdgcn_mfma_f32_16x16x32_bf16(af[i], bv[j], acc[i][j], 0, 0, 0);
    __syncthreads();
    buf ^= 1;
  }

#pragma unroll
  for (int j = 0; j < 4; j++) {
    int col = wn + j * 16 + fr;
    float bb = b1[col];
    int cgc = col >> 3, c7 = col & 7;
#pragma unroll
    for (int i = 0; i < 4; i++)
#pragma unroll
      for (int r = 0; r < 4; r++) {
        int row = i * 16 + fq * 4 + r;
        float v = fmaxf(acc[i][j][r] + bb, 0.f);
        Ts[row * 256 + (((cgc ^ (row & 7)) << 3) | c7)] = f2bf(v);
        acc[i][j][r] = 0.f;
      }
  }
  __syncthreads();

  for (int t = 0; t < 8; t++) {
    if (t + 1 < 8) {
#pragma unroll
      for (int p = 0; p < 4; p++)
        cp16(srcW2[p] + (t + 1) * 32, &Bs[buf ^ 1][(size_t)(p * 256 + wn) * 8]);
    }
    shortx8 af[4], bv[4];
    const int kc = t * 4;
#pragma unroll
    for (int i = 0; i < 4; i++) {
      int row = i * 16 + fr;
      af[i] = *(const shortx8*)&Ts[row * 256 + (((kc + fq) ^ (fr & 7)) << 3)];
    }
#pragma unroll
    for (int j = 0; j < 4; j++) bv[j] = *(const shortx8*)&Bs[buf][offB[j]];
#pragma unroll
    for (int i = 0; i < 4; i++)
#pragma unroll
      for (int j = 0; j < 4; j++)
        acc[i][j] = __builtin_amdgcn_mfma_f32_16x16x32_bf16(af[i], bv[j], acc[i][j], 0, 0, 0);
    __syncthreads();
    buf ^= 1;
  }

#pragma unroll
  for (int j = 0; j < 4; j++) {
    int col = wn + j * 16 + fr;
    float bb = b2[col];
    int cgc = col >> 3, c7 = col & 7;
#pragma unroll
    for (int i = 0; i < 4; i++)
#pragma unroll
      for (int r = 0; r < 4; r++) {
        int row = i * 16 + fq * 4 + r;
        float v = fmaxf(acc[i][j][r] + bb, 0.f);
        Ts[row * 256 + (((cgc ^ (row & 7)) << 3) | c7)] = f2bf(v);
      }
  }
  __syncthreads();
  const int r2 = tid >> 5;
  const int cg2 = tid & 31;
#pragma unroll
  for (int p = 0; p < 8; p++) {
    int row = p * 8 + r2;
    int grow = m0 + row;
    if (grow < M) {
      uint4 v = *(const uint4*)&Ts[row * 256 + ((cg2 ^ (row & 7)) << 3)];
      *(uint4*)&H[(size_t)grow * 256 + cg2 * 8] = v;
    }
  }
}

// ============================================================================
// R27: fused GATHER + MLP (layer 1). Z-stage replaced by gather_stage reading
// Hin + CSR directly (kills gather dispatch + 102 MB Z round-trip). GEMM core
// identical to R22's verified fused_mlp<256>. In/out buffers distinct
// (ping-pong) -- no cross-block in-place hazard.
// ============================================================================
__global__ __launch_bounds__(256, 2)
void fused_mlp_g_kernel(const unsigned short* __restrict__ Hin,  // [M][256]
                        const int* __restrict__ row_ptr,
                        const int* __restrict__ csr,
                        const float* __restrict__ eps, int l,
                        const unsigned short* __restrict__ W1t,  // [256][256]
                        const float* __restrict__ b1,
                        const unsigned short* __restrict__ W2t,  // [256][256]
                        const float* __restrict__ b2,
                        unsigned short* __restrict__ Hout,       // [M][256]
                        int M) {
  __shared__ unsigned short Bs[2][256 * 32];
  __shared__ unsigned short Ts[64 * 256];

  const int m0 = blockIdx.x * 64;
  const int tid = threadIdx.x;
  const int lane = tid & 63;
  const int wave = tid >> 6;
  const int fr = lane & 15;
  const int fq = lane >> 4;
  const int wn = wave * 64;

  const int bn_ = tid >> 2;
  const int bc_ = tid & 3;
  const unsigned short* srcW1[4];
  const unsigned short* srcW2[4];
#pragma unroll
  for (int p = 0; p < 4; p++) {
    int n = p * 64 + bn_;
    int sw = (bc_ ^ ((n >> 1) & 3)) << 3;
    srcW1[p] = W1t + (size_t)n * 256 + sw;
    srcW2[p] = W2t + (size_t)n * 256 + sw;
  }
  int offB[4];
#pragma unroll
  for (int j = 0; j < 4; j++) {
    int n = wn + j * 16 + fr;
    offB[j] = n * 32 + ((fq ^ ((n >> 1) & 3)) << 3);
  }

  // issue W1 panel 0 early (covers under the gather-stage)
#pragma unroll
  for (int p = 0; p < 4; p++)
    cp16(srcW1[p], &Bs[0][(size_t)(p * 256 + wn) * 8]);

  // ---- fused gather-stage: Ts = bf16((1+eps)*H[self] + sum H[nbr]) ----
  gather_stage(Hin, row_ptr, csr, 1.0f + eps[l], m0, M, Ts, tid);

  floatx4 acc[4][4];
#pragma unroll
  for (int i = 0; i < 4; i++)
#pragma unroll
    for (int j = 0; j < 4; j++) acc[i][j] = (floatx4){0.f, 0.f, 0.f, 0.f};

  __syncthreads();  // Ts ds_writes + W1 panel0 cp16 drained & visible
  int buf = 0;

  // ---------------- phase 1: acc = Z @ W1t^T ----------------
  for (int t = 0; t < 8; t++) {
    if (t + 1 < 8) {
#pragma unroll
      for (int p = 0; p < 4; p++)
        cp16(srcW1[p] + (t + 1) * 32, &Bs[buf ^ 1][(size_t)(p * 256 + wn) * 8]);
    } else {
#pragma unroll
      for (int p = 0; p < 4; p++)
        cp16(srcW2[p], &Bs[buf ^ 1][(size_t)(p * 256 + wn) * 8]);
    }
    shortx8 af[4], bv[4];
    const int kc = t * 4;
#pragma unroll
    for (int i = 0; i < 4; i++) {
      int row = i * 16 + fr;
      af[i] = *(const shortx8*)&Ts[row * 256 + (((kc + fq) ^ (fr & 7)) << 3)];
    }
#pragma unroll
    for (int j = 0; j < 4; j++) bv[j] = *(const shortx8*)&Bs[buf][offB[j]];
#pragma unroll
    for (int i = 0; i < 4; i++)
#pragma unroll
      for (int j = 0; j < 4; j++)
        acc[i][j] = __builtin_amdgcn_mfma_f32_16x16x32_bf16(af[i], bv[j], acc[i][j], 0, 0, 0);
    __syncthreads();
    buf ^= 1;
  }

  // ---- T = relu(acc + b1) overwrites Ts ----
#pragma unroll
  for (int j = 0; j < 4; j++) {
    int col = wn + j * 16 + fr;
    float bb = b1[col];
    int cgc = col >> 3, c7 = col & 7;
#pragma unroll
    for (int i = 0; i < 4; i++)
#pragma unroll
      for (int r = 0; r < 4; r++) {
        int row = i * 16 + fq * 4 + r;
        float v = fmaxf(acc[i][j][r] + bb, 0.f);
        Ts[row * 256 + (((cgc ^ (row & 7)) << 3) | c7)] = f2bf(v);
        acc[i][j][r] = 0.f;
      }
  }
  __syncthreads();

  // ---------------- phase 2: acc = T @ W2t^T ----------------
  for (int t = 0; t < 8; t++) {
    if (t + 1 < 8) {
#pragma unroll
      for (int p = 0; p < 4; p++)
        cp16(srcW2[p] + (t + 1) * 32, &Bs[buf ^ 1][(size_t)(p * 256 + wn) * 8]);
    }
    shortx8 af[4], bv[4];
    const int kc = t * 4;
#pragma unroll
    for (int i = 0; i < 4; i++) {
      int row = i * 16 + fr;
      af[i] = *(const shortx8*)&Ts[row * 256 + (((kc + fq) ^ (fr & 7)) << 3)];
    }
#pragma unroll
    for (int j = 0; j < 4; j++) bv[j] = *(const shortx8*)&Bs[buf][offB[j]];
#pragma unroll
    for (int i = 0; i < 4; i++)
#pragma unroll
      for (int j = 0; j < 4; j++)
        acc[i][j] = __builtin_amdgcn_mfma_f32_16x16x32_bf16(af[i], bv[j], acc[i][j], 0, 0, 0);
    __syncthreads();
    buf ^= 1;
  }

  // ---- epilogue: Hout = relu(acc + b2) staged via Ts ----
#pragma unroll
  for (int j = 0; j < 4; j++) {
    int col = wn + j * 16 + fr;
    float bb = b2[col];
    int cgc = col >> 3, c7 = col & 7;
#pragma unroll
    for (int i = 0; i < 4; i++)
#pragma unroll
      for (int r = 0; r < 4; r++) {
        int row = i * 16 + fq * 4 + r;
        float v = fmaxf(acc[i][j][r] + bb, 0.f);
        Ts[row * 256 + (((cgc ^ (row & 7)) << 3) | c7)] = f2bf(v);
      }
  }
  __syncthreads();
  const int r2 = tid >> 5;
  const int cg2 = tid & 31;
#pragma unroll
  for (int p = 0; p < 8; p++) {
    int row = p * 8 + r2;
    int grow = m0 + row;
    if (grow < M) {
      uint4 v = *(const uint4*)&Ts[row * 256 + ((cg2 ^ (row & 7)) << 3)];
      *(uint4*)&Hout[(size_t)grow * 256 + cg2 * 8] = v;
    }
  }
}

// ============================================================================
// R27: fused GATHER + layer-2 + task-dot. Same gather_stage; GEMM core
// identical to R22's verified fused_dot. Per-wave partials -> nodedot4
// plain stores.
// ============================================================================
__global__ __launch_bounds__(256, 2)
void fused_dot_g_kernel(const unsigned short* __restrict__ Hin,  // [M][256]
                        const int* __restrict__ row_ptr,
                        const int* __restrict__ csr,
                        const float* __restrict__ eps, int l,
                        const unsigned short* __restrict__ W1t,  // [512][256]
                        const float* __restrict__ b1,            // [512]
                        const float* __restrict__ w2v,           // [512]
                        float* __restrict__ nodedot4, int M) {
  __shared__ unsigned short Bs[2][256 * 32];
  __shared__ unsigned short Ts[64 * 256];

  const int m0 = blockIdx.x * 64;
  const int tid = threadIdx.x;
  const int lane = tid & 63;
  const int wave = tid >> 6;
  const int fr = lane & 15;
  const int fq = lane >> 4;
  const int wn = wave * 64;

  const int bn_ = tid >> 2;
  const int bc_ = tid & 3;
  const unsigned short* srcW[4];
#pragma unroll
  for (int p = 0; p < 4; p++) {
    int n = p * 64 + bn_;
    srcW[p] = W1t + (size_t)n * 256 + ((bc_ ^ ((n >> 1) & 3)) << 3);
  }
  int offB[4];
#pragma unroll
  for (int j = 0; j < 4; j++) {
    int n = wn + j * 16 + fr;
    offB[j] = n * 32 + ((fq ^ ((n >> 1) & 3)) << 3);
  }

  // issue W panel 0 early (covers under the gather-stage)
#pragma unroll
  for (int p = 0; p < 4; p++)
    cp16(srcW[p], &Bs[0][(size_t)(p * 256 + wn) * 8]);

  // ---- fused gather-stage ----
  gather_stage(Hin, row_ptr, csr, 1.0f + eps[l], m0, M, Ts, tid);

  float pd[4][4];
#pragma unroll
  for (int i = 0; i < 4; i++)
#pragma unroll
    for (int r = 0; r < 4; r++) pd[i][r] = 0.f;

  floatx4 acc[4][4];
#pragma unroll
  for (int i = 0; i < 4; i++)
#pragma unroll
    for (int j = 0; j < 4; j++) acc[i][j] = (floatx4){0.f, 0.f, 0.f, 0.f};

  __syncthreads();  // Ts ds_writes + panel0 cp16 drained & visible
  int buf = 0;

  // 16 flattened K-steps: s = nh*8 + t; panel offset = nh*65536 + t*32
  for (int s = 0; s < 16; s++) {
    int ns = s + 1;
    if (ns < 16) {
      const size_t off = (size_t)(ns >> 3) * 65536 + (size_t)(ns & 7) * 32;
#pragma unroll
      for (int p = 0; p < 4; p++)
        cp16(srcW[p] + off, &Bs[buf ^ 1][(size_t)(p * 256 + wn) * 8]);
    }
    shortx8 af[4], bv[4];
    const int kc = (s & 7) * 4;
#pragma unroll
    for (int i = 0; i < 4; i++) {
      int row = i * 16 + fr;
      af[i] = *(const shortx8*)&Ts[row * 256 + (((kc + fq) ^ (fr & 7)) << 3)];
    }
#pragma unroll
    for (int j = 0; j < 4; j++) bv[j] = *(const shortx8*)&Bs[buf][offB[j]];
#pragma unroll
    for (int i = 0; i < 4; i++)
#pragma unroll
      for (int j = 0; j < 4; j++)
        acc[i][j] = __builtin_amdgcn_mfma_f32_16x16x32_bf16(af[i], bv[j], acc[i][j], 0, 0, 0);
    __syncthreads();
    buf ^= 1;

    if ((s & 7) == 7) {  // end of a 256-col half: fold into pd, reset acc
      const int nh = s >> 3;
#pragma unroll
      for (int j = 0; j < 4; j++) {
        int col = nh * 256 + wn + j * 16 + fr;
        float bb = b1[col];
        float wv = w2v[col];
#pragma unroll
        for (int i = 0; i < 4; i++)
#pragma unroll
          for (int r = 0; r < 4; r++) {
            pd[i][r] += fmaxf(acc[i][j][r] + bb, 0.f) * wv;
            acc[i][j][r] = 0.f;
          }
      }
    }
  }

#pragma unroll
  for (int i = 0; i < 4; i++)
#pragma unroll
    for (int r = 0; r < 4; r++) {
      float s = pd[i][r];
#pragma unroll
      for (int off = 1; off < 16; off <<= 1) s += __shfl_xor(s, off);
      if (fr == 0) {
        int row = m0 + i * 16 + fq * 4 + r;
        if (row < M) nodedot4[(size_t)wave * N_NODES + row] = s;
      }
    }
}

// ---------------- readout ----------------------------------------------------
// R22 (kept): one thread per node; wave-level key-segmented inclusive scan.
__global__ __launch_bounds__(256)
void pool_kernel(const float* __restrict__ nodedot4, const int* __restrict__ batch,
                 float* __restrict__ out, const float* __restrict__ c2p) {
  const int i = blockIdx.x * 256 + threadIdx.x;
  if (i >= N_NODES) return;
  const int lane = threadIdx.x & 63;
  const float c2 = *c2p;
  float v = (nodedot4[i] + nodedot4[N_NODES + i]) +
            (nodedot4[2 * N_NODES + i] + nodedot4[3 * N_NODES + i]) + c2;
  const int g = batch[i];
  float s = v;
#pragma unroll
  for (int off = 1; off < 64; off <<= 1) {
    float u = __shfl_up(s, off);
    int gu = __shfl_up(g, off);
    if (lane >= off && gu == g) s += u;
  }
  bool last = (i == N_NODES - 1) || (batch[i + 1] != g) || (lane == 63);
  if (last) unsafeAtomicAdd(&out[g], s);
}

extern "C" void kernel_launch(void* const* d_in, const int* in_sizes, int n_in,
                              void* d_out, int out_size, void* d_ws, size_t ws_size,
                              hipStream_t stream) {
  const float* x       = (const float*)d_in[0];
  const int*   ei      = (const int*)d_in[1];
  const int*   batch   = (const int*)d_in[2];
  const float* W_embed = (const float*)d_in[3];
  const float* b_embed = (const float*)d_in[4];
  const float* eps     = (const float*)d_in[5];
  const float* W1[3] = {(const float*)d_in[6],  (const float*)d_in[10], (const float*)d_in[14]};
  const float* B1[3] = {(const float*)d_in[7],  (const float*)d_in[11], (const float*)d_in[15]};
  const float* W2[3] = {(const float*)d_in[8],  (const float*)d_in[12], (const float*)d_in[16]};
  const float* B2[3] = {(const float*)d_in[9],  (const float*)d_in[13], (const float*)d_in[17]};
  const float* W_task = (const float*)d_in[18];
  const float* b_task = (const float*)d_in[19];
  float* out = (float*)d_out;

  const size_t OFF_ND4 = 51200000;   // 4x100000 floats
  const size_t OFF_RZ  = 102400000;  // G (layer0) then H2 (layer1 out)
  const size_t OFF_AUX = 153600000;
  if (ws_size < OFF_AUX + 4000000) return;
  unsigned short* RH = (unsigned short*)d_ws;
  float* nodedot4 = (float*)((char*)d_ws + OFF_ND4);
  unsigned short* RZ = (unsigned short*)((char*)d_ws + OFF_RZ);
  char* aux = (char*)d_ws + OFF_AUX;
  int* row_ptr  = (int*)(aux);               // 100001 ints
  int* cursor   = (int*)(aux + 400016);      // 100000 ints (also deg histogram)
  int* csr_src  = (int*)(aux + 800016);      // 300000 ints
  int* blk_sums = (int*)(aux + 2000016);     // 98 ints
  int* blk_off  = (int*)(aux + 2000416);     // 98 ints
  unsigned short* WT = (unsigned short*)(aux + 2400832);  // 360448 bf16
  float* w2v = (float*)(aux + 3200832);      // 512 floats
  float* c2  = (float*)(aux + 3202880);      // 1 float
  unsigned short* WfT    = WT;
  unsigned short* Wt2_0  = WT + 32768;
  unsigned short* Wt1_1  = WT + 98304;
  unsigned short* Wt2_1  = WT + 163840;
  unsigned short* Wt1_2  = WT + 229376;

  // ---- prep: all independent prologue work (1 dispatch; zeroes cursor) ----
  PrepArgs pa;
  pa.W[0] = W2[0]; pa.Wt[0] = Wt2_0; pa.K[0] = 256; pa.N[0] = 256;
  pa.W[1] = W1[1]; pa.Wt[1] = Wt1_1; pa.K[1] = 256; pa.N[1] = 256;
  pa.W[2] = W2[1]; pa.Wt[2] = Wt2_1; pa.K[2] = 256; pa.N[2] = 256;
  pa.W[3] = W1[2]; pa.Wt[3] = Wt1_2; pa.K[3] = 256; pa.N[3] = 512;
  pa.We = W_embed; pa.be = b_embed; pa.W1_0 = W1[0]; pa.WfT = WfT;
  pa.W2_2 = W2[2]; pa.b2_2 = B2[2]; pa.wtask = W_task; pa.w2v = w2v; pa.c2 = c2;
  pa.nodedot = (float*)cursor;  // zero cursor here (0.0f bits == 0)
  pa.out = out; pa.b_task = b_task;
  prep_kernel<<<889, 256, 0, stream>>>(pa);

  // ---- CSR build ----
  hist_kernel<<<(E_EDGES + 255) / 256, 256, 0, stream>>>(ei, cursor);
  scan_blk_kernel<<<98, 256, 0, stream>>>(cursor, row_ptr, blk_sums, N_NODES, N_NODES + 1);
  scan_blk_kernel<<<1, 256, 0, stream>>>(blk_sums, blk_off, nullptr, 98, 98);
  scan_fix_kernel<<<(N_NODES + 256) / 256, 256, 0, stream>>>(row_ptr, blk_off, cursor);
  fill_kernel<<<(E_EDGES + 255) / 256, 256, 0, stream>>>(ei, cursor, csr_src);

  const int FB = (N_NODES + 63) / 64;  // 1563 fused blocks (64 rows each)

  // ---- layer 0 (folded embed): G -> RH ----
  gatherx_kernel<<<N_NODES / 4, 256, 0, stream>>>(x, RZ, row_ptr, csr_src, eps);
  fused_mlp_kernel<64><<<FB, 256, 0, stream>>>(RZ, WfT, B1[0], Wt2_0, B2[0], RH, N_NODES);

  // ---- layer 1: fused gather+MLP, RH -> RZ (ping-pong; G dead) ----
  fused_mlp_g_kernel<<<FB, 256, 0, stream>>>(RH, row_ptr, csr_src, eps, 1,
                                             Wt1_1, B1[1], Wt2_1, B2[1], RZ, N_NODES);

  // ---- layer 2: fused gather+GEMM+task-dot, RZ -> nodedot4 ----
  fused_dot_g_kernel<<<FB, 256, 0, stream>>>(RZ, row_ptr, csr_src, eps, 2,
                                             Wt1_2, B1[2], w2v, nodedot4, N_NODES);

  // ---- out[g] = b_task + sum_i (sum_w nodedot4[w][i] + c2) ----
  pool_kernel<<<(N_NODES + 255) / 256, 256, 0, stream>>>(nodedot4, batch, out, c2);
}

// Round 13
// 396.768 us; speedup vs baseline: 1.5522x; 1.0940x over previous
//
#include <hip/hip_runtime.h>

#define N_NODES 100000
#define E_EDGES 300000
#define N_GRAPHS 2048

typedef float  floatx4 __attribute__((ext_vector_type(4)));
typedef short  shortx8 __attribute__((ext_vector_type(8)));

__device__ __forceinline__ float bf2f(unsigned short u) {
  return __uint_as_float(((unsigned int)u) << 16);
}
__device__ __forceinline__ unsigned short f2bf(float f) {
  unsigned int u = __float_as_uint(f);
  u += 0x7FFFu + ((u >> 16) & 1u);
  return (unsigned short)(u >> 16);
}

// async global->LDS, 16B per lane; lds base wave-uniform, dst = base+lane*16 (m104)
__device__ __forceinline__ void cp16(const void* g, void* l) {
  __builtin_amdgcn_global_load_lds(
      (const __attribute__((address_space(1))) unsigned int*)g,
      (__attribute__((address_space(3))) unsigned int*)l, 16, 0, 0);
}

// ---- prep kernel: all independent prologue work in ONE dispatch -------------
// Blocks [490,881) zero CURSOR (deg histogram) -> zero_kernel dispatch dropped.
struct PrepArgs {
  const float* W[4];
  unsigned short* Wt[4];
  int K[4];
  int N[4];
  const float* We;
  const float* be;
  const float* W1_0;
  unsigned short* WfT;
  const float* W2_2;
  const float* b2_2;
  const float* wtask;
  float* w2v;
  float* c2;
  float* nodedot;   // points at cursor (int*) -- 0.0f bits == int 0
  float* out;
  const float* b_task;
};

__global__ __launch_bounds__(256)
void prep_kernel(PrepArgs a) {
  const int blk = blockIdx.x;
  if (blk < 320) {
    int z, b;
    if (blk < 64)       { z = 0; b = blk; }
    else if (blk < 128) { z = 1; b = blk - 64; }
    else if (blk < 192) { z = 2; b = blk - 128; }
    else                { z = 3; b = blk - 192; }
    const int K = a.K[z], N = a.N[z];
    const int nt = N / 32;
    const int kb = (b / nt) * 32, nb = (b % nt) * 32;
    __shared__ unsigned short tile[32][33];
    const float* W = a.W[z];
    unsigned short* Wt = a.Wt[z];
    const int tx = threadIdx.x & 31, ty = threadIdx.x >> 5;
    for (int r = ty; r < 32; r += 8)
      tile[r][tx] = f2bf(W[(size_t)(kb + r) * N + nb + tx]);
    __syncthreads();
    for (int r = ty; r < 32; r += 8)
      Wt[(size_t)(nb + r) * K + kb + tx] = tile[tx][r];
  } else if (blk < 361) {
    const int k = blk - 320;  // 0..40
    const int n = threadIdx.x;
    if (k < 40) {
      float s = 0.f;
      for (int j = 0; j < 128; j++) s = fmaf(a.We[k * 128 + j], a.W1_0[(size_t)j * 256 + n], s);
      a.WfT[n * 64 + k] = f2bf(s);
    } else {
      float s = 0.f;
      for (int j = 0; j < 128; j++) s = fmaf(a.be[j], a.W1_0[(size_t)j * 256 + n], s);
      a.WfT[n * 64 + 40] = f2bf(s);
      for (int kk = 41; kk < 64; kk++) a.WfT[n * 64 + kk] = 0;
    }
  } else if (blk < 490) {
    const int p = blk - 361;  // 0..128
    const int lane = threadIdx.x & 63;
    const int wave = threadIdx.x >> 6;
    if (p < 128) {
      const int k = p * 4 + wave;
      const float* row = a.W2_2 + (size_t)k * 512 + lane * 8;
      float4 a0 = *(const float4*)(row);
      float4 a1 = *(const float4*)(row + 4);
      float4 w0 = *(const float4*)(a.wtask + lane * 8);
      float4 w1 = *(const float4*)(a.wtask + lane * 8 + 4);
      float s = a0.x * w0.x + a0.y * w0.y + a0.z * w0.z + a0.w * w0.w +
                a1.x * w1.x + a1.y * w1.y + a1.z * w1.z + a1.w * w1.w;
#pragma unroll
      for (int off = 32; off > 0; off >>= 1) s += __shfl_down(s, off);
      if (lane == 0) a.w2v[k] = s;
    } else if (wave == 0) {
      float4 a0 = *(const float4*)(a.b2_2 + lane * 8);
      float4 a1 = *(const float4*)(a.b2_2 + lane * 8 + 4);
      float4 w0 = *(const float4*)(a.wtask + lane * 8);
      float4 w1 = *(const float4*)(a.wtask + lane * 8 + 4);
      float s = a0.x * w0.x + a0.y * w0.y + a0.z * w0.z + a0.w * w0.w +
                a1.x * w1.x + a1.y * w1.y + a1.z * w1.z + a1.w * w1.w;
#pragma unroll
      for (int off = 32; off > 0; off >>= 1) s += __shfl_down(s, off);
      if (lane == 0) *a.c2 = s;
    }
  } else if (blk < 881) {
    int i = (blk - 490) * 256 + threadIdx.x;
    if (i < N_NODES) a.nodedot[i] = 0.f;  // zeroes cursor (int 0 bits)
  } else {
    int g = (blk - 881) * 256 + threadIdx.x;
    if (g < N_GRAPHS) a.out[g] = a.b_task[0];
  }
}

// ---------------- CSR build: histogram, scan, fill ---------------------------
__global__ __launch_bounds__(256)
void hist_kernel(const int* __restrict__ ei, int* __restrict__ deg) {
  int e = blockIdx.x * 256 + threadIdx.x;
  if (e < E_EDGES) atomicAdd(&deg[ei[E_EDGES + e]], 1);
}

__global__ __launch_bounds__(256)
void scan_blk_kernel(const int* __restrict__ in, int* __restrict__ out,
                     int* __restrict__ blk_sums, int n_in, int n_out) {
  __shared__ int sm[256];
  const int t = threadIdx.x;
  const int base = blockIdx.x * 1024 + t * 4;
  int d0 = (base + 0 < n_in) ? in[base + 0] : 0;
  int d1 = (base + 1 < n_in) ? in[base + 1] : 0;
  int d2 = (base + 2 < n_in) ? in[base + 2] : 0;
  int d3 = (base + 3 < n_in) ? in[base + 3] : 0;
  int s = d0 + d1 + d2 + d3;
  sm[t] = s;
  __syncthreads();
  for (int off = 1; off < 256; off <<= 1) {
    int v = (t >= off) ? sm[t - off] : 0;
    __syncthreads();
    sm[t] += v;
    __syncthreads();
  }
  int excl = sm[t] - s;
  if (base + 0 < n_out) out[base + 0] = excl;
  if (base + 1 < n_out) out[base + 1] = excl + d0;
  if (base + 2 < n_out) out[base + 2] = excl + d0 + d1;
  if (base + 3 < n_out) out[base + 3] = excl + d0 + d1 + d2;
  if (t == 255 && blk_sums) blk_sums[blockIdx.x] = sm[255];
}

__global__ __launch_bounds__(256)
void scan_fix_kernel(int* __restrict__ row_ptr, const int* __restrict__ blk_off,
                     int* __restrict__ cursor) {
  int i = blockIdx.x * 256 + threadIdx.x;
  if (i <= N_NODES) {
    int v = row_ptr[i] + blk_off[i >> 10];
    row_ptr[i] = v;
    if (i < N_NODES) cursor[i] = v;
  }
}

__global__ __launch_bounds__(256)
void fill_kernel(const int* __restrict__ ei, int* __restrict__ cursor,
                 int* __restrict__ csr_src) {
  int e = blockIdx.x * 256 + threadIdx.x;
  if (e < E_EDGES) {
    int d = ei[E_EDGES + e];
    int slot = atomicAdd(&cursor[d], 1);
    csr_src[slot] = ei[e];
  }
}

// ---- gatherx: G[n,64] = bf16([(1+eps)X_n + sum X_src | f_n | 0...]) ---------
__global__ __launch_bounds__(256)
void gatherx_kernel(const float* __restrict__ X, unsigned short* __restrict__ G,
                    const int* __restrict__ row_ptr, const int* __restrict__ csr,
                    const float* __restrict__ eps) {
  const int node = blockIdx.x * 4 + (threadIdx.x >> 6);
  const int lane = threadIdx.x & 63;
  const float sc = 1.0f + eps[0];
  const int e0 = row_ptr[node];
  const int e1 = row_ptr[node + 1];
  float acc = 0.f;
  if (lane < 40) {
    acc = sc * X[(size_t)node * 40 + lane];
    int e = e0;
    for (; e + 4 <= e1; e += 4) {
      int s0 = csr[e], s1 = csr[e + 1], s2 = csr[e + 2], s3 = csr[e + 3];
      float a0 = X[(size_t)s0 * 40 + lane];
      float a1 = X[(size_t)s1 * 40 + lane];
      float a2 = X[(size_t)s2 * 40 + lane];
      float a3 = X[(size_t)s3 * 40 + lane];
      acc += (a0 + a1) + (a2 + a3);
    }
    for (; e < e1; e++)
      acc += X[(size_t)csr[e] * 40 + lane];
  } else if (lane == 40) {
    acc = sc + (float)(e1 - e0);
  }
  G[(size_t)node * 64 + lane] = f2bf(acc);
}

// ------- gather (D=256): Z[d] = bf16((1+eps)*H[d] + sum H[src]) --------------
// R25 paired-uint4 form: lanes 0-31 read neighbor e, lanes 32-63 read e+1
// (16B/lane -> two 512B rows/wave-load); fold with one __shfl_down(.,32).
__global__ __launch_bounds__(256)
void gather_kernel(const unsigned short* __restrict__ H, unsigned short* __restrict__ Z,
                   const int* __restrict__ row_ptr, const int* __restrict__ csr,
                   const float* __restrict__ eps, int l) {
  const int node = blockIdx.x * 4 + (threadIdx.x >> 6);
  const int lane = threadIdx.x & 63;
  const int half = lane >> 5;   // 0: lanes 0-31, 1: lanes 32-63
  const int hl = lane & 31;     // dim-chunk within row (8 bf16 each)
  const float sc = 1.0f + eps[l];
  float acc[8];
#pragma unroll
  for (int k = 0; k < 8; k++) acc[k] = 0.f;

  if (half == 0) {
    uint4 v = *(const uint4*)(H + (size_t)node * 256 + hl * 8);
    acc[0] = sc * bf2f((unsigned short)(v.x & 0xFFFF));
    acc[1] = sc * bf2f((unsigned short)(v.x >> 16));
    acc[2] = sc * bf2f((unsigned short)(v.y & 0xFFFF));
    acc[3] = sc * bf2f((unsigned short)(v.y >> 16));
    acc[4] = sc * bf2f((unsigned short)(v.z & 0xFFFF));
    acc[5] = sc * bf2f((unsigned short)(v.z >> 16));
    acc[6] = sc * bf2f((unsigned short)(v.w & 0xFFFF));
    acc[7] = sc * bf2f((unsigned short)(v.w >> 16));
  }

  const int e0 = row_ptr[node];
  const int e1 = row_ptr[node + 1];
  int e = e0;
  for (; e + 2 <= e1; e += 2) {
    int s = csr[e + half];
    uint4 v = *(const uint4*)(H + (size_t)s * 256 + hl * 8);
    acc[0] += bf2f((unsigned short)(v.x & 0xFFFF));
    acc[1] += bf2f((unsigned short)(v.x >> 16));
    acc[2] += bf2f((unsigned short)(v.y & 0xFFFF));
    acc[3] += bf2f((unsigned short)(v.y >> 16));
    acc[4] += bf2f((unsigned short)(v.z & 0xFFFF));
    acc[5] += bf2f((unsigned short)(v.z >> 16));
    acc[6] += bf2f((unsigned short)(v.w & 0xFFFF));
    acc[7] += bf2f((unsigned short)(v.w >> 16));
  }
  if (e < e1 && half == 0) {  // odd-degree tail
    int s = csr[e];
    uint4 v = *(const uint4*)(H + (size_t)s * 256 + hl * 8);
    acc[0] += bf2f((unsigned short)(v.x & 0xFFFF));
    acc[1] += bf2f((unsigned short)(v.x >> 16));
    acc[2] += bf2f((unsigned short)(v.y & 0xFFFF));
    acc[3] += bf2f((unsigned short)(v.y >> 16));
    acc[4] += bf2f((unsigned short)(v.z & 0xFFFF));
    acc[5] += bf2f((unsigned short)(v.z >> 16));
    acc[6] += bf2f((unsigned short)(v.w & 0xFFFF));
    acc[7] += bf2f((unsigned short)(v.w >> 16));
  }

#pragma unroll
  for (int k = 0; k < 8; k++) acc[k] += __shfl_down(acc[k], 32);

  if (half == 0) {
    unsigned short z[8];
#pragma unroll
    for (int k = 0; k < 8; k++) z[k] = f2bf(acc[k]);
    *(uint4*)(Z + (size_t)node * 256 + hl * 8) = *(const uint4*)z;
  }
}

// ============================================================================
// R22/R25 (verbatim, FINAL): fused per-layer MLP with minimum 2-phase pipeline
// (T3-min): per K-step {stage panel t+1 -> Bs[buf^1]; ds_read panel t; MFMA;
// ONE __syncthreads}. W-panel L2 latency hides under MFMA. 64 KB LDS -> 2
// blocks/CU. Swizzles verified in R19.
// POST-MORTEM LEDGER for the K-loop (why this form is terminal):
//   R23/R24/R28 counted-vmcnt / barrier-free variants: flaky races (cp16's
//   async LDS-write-landing vs in-order ds_read-execute is not orderable at
//   HIP source without draining) -> 3 correctness failures.
//   R20 direct-B-to-VGPR: latency-serial + scratch (520us). R26 reg-prefetch:
//   VGPR spill storm (616us). Plain __syncthreads 2-phase = stable optimum.
// ============================================================================
template <int K1>
__global__ __launch_bounds__(256, 2)
void fused_mlp_kernel(const unsigned short* __restrict__ A,    // [M][K1]
                      const unsigned short* __restrict__ W1t,  // [256][K1]
                      const float* __restrict__ b1,            // [256]
                      const unsigned short* __restrict__ W2t,  // [256][256]
                      const float* __restrict__ b2,            // [256]
                      unsigned short* __restrict__ H,          // [M][256]
                      int M) {
  constexpr int ACH = K1 / 8;           // 16B chunks per A row (8 or 32)
  constexpr int ZP = (64 * ACH) / 256;  // cp16 issues/thread for Z (2 or 8)
  constexpr int NT1 = K1 / 32;          // phase-1 K-steps (2 or 8)

  __shared__ unsigned short Bs[2][256 * 32];  // 2 x 16 KB W-panel dbuf
  __shared__ unsigned short Ts[64 * 256];     // 32 KB (Z then T then H-stage)

  const int m0 = blockIdx.x * 64;
  const int tid = threadIdx.x;
  const int lane = tid & 63;
  const int wave = tid >> 6;
  const int fr = lane & 15;
  const int fq = lane >> 4;
  const int wn = wave * 64;

  // ---- stage Z once into Ts (per-lane pre-swizzled global source) ----
#pragma unroll
  for (int p = 0; p < ZP; p++) {
    int slot = p * 256 + tid;
    int row = slot / ACH;
    int cs = slot % ACH;
    int cg = cs ^ (row & 7);
    int grow = m0 + row;
    if (grow >= M) grow = M - 1;
    cp16(A + (size_t)grow * K1 + cg * 8, Ts + (size_t)(p * 256 + wn) * 8);
  }

  // ---- B staging source pointers (pre-swizzled, R19-verified) ----
  const int bn_ = tid >> 2;
  const int bc_ = tid & 3;
  const unsigned short* srcW1[4];
  const unsigned short* srcW2[4];
#pragma unroll
  for (int p = 0; p < 4; p++) {
    int n = p * 64 + bn_;
    int sw = (bc_ ^ ((n >> 1) & 3)) << 3;
    srcW1[p] = W1t + (size_t)n * K1 + sw;
    srcW2[p] = W2t + (size_t)n * 256 + sw;
  }

  // ---- B-frag LDS offsets (constant across K-steps) ----
  int offB[4];
#pragma unroll
  for (int j = 0; j < 4; j++) {
    int n = wn + j * 16 + fr;
    offB[j] = n * 32 + ((fq ^ ((n >> 1) & 3)) << 3);
  }

  // ---- stage W1 panel 0 into Bs[0] ----
#pragma unroll
  for (int p = 0; p < 4; p++)
    cp16(srcW1[p], &Bs[0][(size_t)(p * 256 + wn) * 8]);

  floatx4 acc[4][4];
#pragma unroll
  for (int i = 0; i < 4; i++)
#pragma unroll
    for (int j = 0; j < 4; j++) acc[i][j] = (floatx4){0.f, 0.f, 0.f, 0.f};

  __syncthreads();  // Z + W1 panel 0 staged & visible
  int buf = 0;

  // ---------------- phase 1: acc = Z @ W1t^T ----------------
  for (int t = 0; t < NT1; t++) {
    // prefetch next panel (last step prefetches W2 panel 0)
    if (t + 1 < NT1) {
#pragma unroll
      for (int p = 0; p < 4; p++)
        cp16(srcW1[p] + (t + 1) * 32, &Bs[buf ^ 1][(size_t)(p * 256 + wn) * 8]);
    } else {
#pragma unroll
      for (int p = 0; p < 4; p++)
        cp16(srcW2[p], &Bs[buf ^ 1][(size_t)(p * 256 + wn) * 8]);
    }
    shortx8 af[4], bv[4];
    const int kc = t * 4;
#pragma unroll
    for (int i = 0; i < 4; i++) {
      int row = i * 16 + fr;
      af[i] = *(const shortx8*)&Ts[row * K1 + (((kc + fq) ^ (fr & 7)) << 3)];
    }
#pragma unroll
    for (int j = 0; j < 4; j++) bv[j] = *(const shortx8*)&Bs[buf][offB[j]];
#pragma unroll
    for (int i = 0; i < 4; i++)
#pragma unroll
      for (int j = 0; j < 4; j++)
        acc[i][j] = __builtin_amdgcn_mfma_f32_16x16x32_bf16(af[i], bv[j], acc[i][j], 0, 0, 0);
    __syncthreads();  // drains prefetch (after compute) + orders buffer reuse
    buf ^= 1;
  }

  // ---- T = relu(acc + b1) overwrites Ts (all Ts reads done: loop-end sync) --
#pragma unroll
  for (int j = 0; j < 4; j++) {
    int col = wn + j * 16 + fr;
    float bb = b1[col];
    int cgc = col >> 3, c7 = col & 7;
#pragma unroll
    for (int i = 0; i < 4; i++)
#pragma unroll
      for (int r = 0; r < 4; r++) {
        int row = i * 16 + fq * 4 + r;
        float v = fmaxf(acc[i][j][r] + bb, 0.f);
        Ts[row * 256 + (((cgc ^ (row & 7)) << 3) | c7)] = f2bf(v);
        acc[i][j][r] = 0.f;
      }
  }
  __syncthreads();  // T visible; Bs[buf] holds W2 panel 0

  // ---------------- phase 2: acc = T @ W2t^T ----------------
  for (int t = 0; t < 8; t++) {
    if (t + 1 < 8) {
#pragma unroll
      for (int p = 0; p < 4; p++)
        cp16(srcW2[p] + (t + 1) * 32, &Bs[buf ^ 1][(size_t)(p * 256 + wn) * 8]);
    }
    shortx8 af[4], bv[4];
    const int kc = t * 4;
#pragma unroll
    for (int i = 0; i < 4; i++) {
      int row = i * 16 + fr;
      af[i] = *(const shortx8*)&Ts[row * 256 + (((kc + fq) ^ (fr & 7)) << 3)];
    }
#pragma unroll
    for (int j = 0; j < 4; j++) bv[j] = *(const shortx8*)&Bs[buf][offB[j]];
#pragma unroll
    for (int i = 0; i < 4; i++)
#pragma unroll
      for (int j = 0; j < 4; j++)
        acc[i][j] = __builtin_amdgcn_mfma_f32_16x16x32_bf16(af[i], bv[j], acc[i][j], 0, 0, 0);
    __syncthreads();
    buf ^= 1;
  }

  // ---- epilogue: H = relu(acc + b2), staged via Ts for coalesced stores ----
#pragma unroll
  for (int j = 0; j < 4; j++) {
    int col = wn + j * 16 + fr;
    float bb = b2[col];
    int cgc = col >> 3, c7 = col & 7;
#pragma unroll
    for (int i = 0; i < 4; i++)
#pragma unroll
      for (int r = 0; r < 4; r++) {
        int row = i * 16 + fq * 4 + r;
        float v = fmaxf(acc[i][j][r] + bb, 0.f);
        Ts[row * 256 + (((cgc ^ (row & 7)) << 3) | c7)] = f2bf(v);
      }
  }
  __syncthreads();
  const int r2 = tid >> 5;    // 0..7
  const int cg2 = tid & 31;   // output 16B chunk
#pragma unroll
  for (int p = 0; p < 8; p++) {
    int row = p * 8 + r2;
    int grow = m0 + row;
    if (grow < M) {
      uint4 v = *(const uint4*)&Ts[row * 256 + ((cg2 ^ (row & 7)) << 3)];
      *(uint4*)&H[(size_t)grow * 256 + cg2 * 8] = v;
    }
  }
}

// ============================================================================
// R22/R25 (verbatim, FINAL): fused layer-2 + task-dot, 2-phase pipeline, 16
// flattened K-steps; per-wave partials -> nodedot4[wave][row] PLAIN stores.
// ============================================================================
__global__ __launch_bounds__(256, 2)
void fused_dot_kernel(const unsigned short* __restrict__ A,    // Z [M][256]
                      const unsigned short* __restrict__ W1t,  // [512][256]
                      const float* __restrict__ b1,            // [512]
                      const float* __restrict__ w2v,           // [512]
                      float* __restrict__ nodedot4, int M) {
  __shared__ unsigned short Bs[2][256 * 32];  // 2 x 16 KB
  __shared__ unsigned short Ts[64 * 256];     // 32 KB (Z)

  const int m0 = blockIdx.x * 64;
  const int tid = threadIdx.x;
  const int lane = tid & 63;
  const int wave = tid >> 6;
  const int fr = lane & 15;
  const int fq = lane >> 4;
  const int wn = wave * 64;

#pragma unroll
  for (int p = 0; p < 8; p++) {
    int slot = p * 256 + tid;
    int row = slot >> 5;
    int cs = slot & 31;
    int cg = cs ^ (row & 7);
    int grow = m0 + row;
    if (grow >= M) grow = M - 1;
    cp16(A + (size_t)grow * 256 + cg * 8, Ts + (size_t)(p * 256 + wn) * 8);
  }

  const int bn_ = tid >> 2;
  const int bc_ = tid & 3;
  const unsigned short* srcW[4];
#pragma unroll
  for (int p = 0; p < 4; p++) {
    int n = p * 64 + bn_;
    srcW[p] = W1t + (size_t)n * 256 + ((bc_ ^ ((n >> 1) & 3)) << 3);
  }
  int offB[4];
#pragma unroll
  for (int j = 0; j < 4; j++) {
    int n = wn + j * 16 + fr;
    offB[j] = n * 32 + ((fq ^ ((n >> 1) & 3)) << 3);
  }

  // stage W panel for step 0 (nh=0, k0=0)
#pragma unroll
  for (int p = 0; p < 4; p++)
    cp16(srcW[p], &Bs[0][(size_t)(p * 256 + wn) * 8]);

  float pd[4][4];
#pragma unroll
  for (int i = 0; i < 4; i++)
#pragma unroll
    for (int r = 0; r < 4; r++) pd[i][r] = 0.f;

  floatx4 acc[4][4];
#pragma unroll
  for (int i = 0; i < 4; i++)
#pragma unroll
    for (int j = 0; j < 4; j++) acc[i][j] = (floatx4){0.f, 0.f, 0.f, 0.f};

  __syncthreads();  // Z + panel 0 staged
  int buf = 0;

  // 16 flattened K-steps: s = nh*8 + t; panel offset = nh*65536 + t*32
  for (int s = 0; s < 16; s++) {
    int ns = s + 1;
    if (ns < 16) {
      const size_t off = (size_t)(ns >> 3) * 65536 + (size_t)(ns & 7) * 32;
#pragma unroll
      for (int p = 0; p < 4; p++)
        cp16(srcW[p] + off, &Bs[buf ^ 1][(size_t)(p * 256 + wn) * 8]);
    }
    shortx8 af[4], bv[4];
    const int kc = (s & 7) * 4;
#pragma unroll
    for (int i = 0; i < 4; i++) {
      int row = i * 16 + fr;
      af[i] = *(const shortx8*)&Ts[row * 256 + (((kc + fq) ^ (fr & 7)) << 3)];
    }
#pragma unroll
    for (int j = 0; j < 4; j++) bv[j] = *(const shortx8*)&Bs[buf][offB[j]];
#pragma unroll
    for (int i = 0; i < 4; i++)
#pragma unroll
      for (int j = 0; j < 4; j++)
        acc[i][j] = __builtin_amdgcn_mfma_f32_16x16x32_bf16(af[i], bv[j], acc[i][j], 0, 0, 0);
    __syncthreads();
    buf ^= 1;

    if ((s & 7) == 7) {  // end of a 256-col half: fold into pd, reset acc
      const int nh = s >> 3;
#pragma unroll
      for (int j = 0; j < 4; j++) {
        int col = nh * 256 + wn + j * 16 + fr;
        float bb = b1[col];
        float wv = w2v[col];
#pragma unroll
        for (int i = 0; i < 4; i++)
#pragma unroll
          for (int r = 0; r < 4; r++) {
            pd[i][r] += fmaxf(acc[i][j][r] + bb, 0.f) * wv;
            acc[i][j][r] = 0.f;
          }
      }
    }
  }

#pragma unroll
  for (int i = 0; i < 4; i++)
#pragma unroll
    for (int r = 0; r < 4; r++) {
      float s = pd[i][r];
#pragma unroll
      for (int off = 1; off < 16; off <<= 1) s += __shfl_xor(s, off);
      if (fr == 0) {
        int row = m0 + i * 16 + fq * 4 + r;
        // plain store: plane `wave`, row owned by exactly this block
        if (row < M) nodedot4[(size_t)wave * N_NODES + row] = s;
      }
    }
}

// ---------------- readout ----------------------------------------------------
// R22 (kept): one thread per node; wave-level key-segmented inclusive scan
// (batch sorted) -> ~one atomicAdd per graph-run per wave.
__global__ __launch_bounds__(256)
void pool_kernel(const float* __restrict__ nodedot4, const int* __restrict__ batch,
                 float* __restrict__ out, const float* __restrict__ c2p) {
  const int i = blockIdx.x * 256 + threadIdx.x;
  if (i >= N_NODES) return;
  const int lane = threadIdx.x & 63;
  const float c2 = *c2p;
  float v = (nodedot4[i] + nodedot4[N_NODES + i]) +
            (nodedot4[2 * N_NODES + i] + nodedot4[3 * N_NODES + i]) + c2;
  const int g = batch[i];
  float s = v;
#pragma unroll
  for (int off = 1; off < 64; off <<= 1) {
    float u = __shfl_up(s, off);
    int gu = __shfl_up(g, off);
    if (lane >= off && gu == g) s += u;
  }
  bool last = (i == N_NODES - 1) || (batch[i + 1] != g) || (lane == 63);
  if (last) unsafeAtomicAdd(&out[g], s);
}

extern "C" void kernel_launch(void* const* d_in, const int* in_sizes, int n_in,
                              void* d_out, int out_size, void* d_ws, size_t ws_size,
                              hipStream_t stream) {
  const float* x       = (const float*)d_in[0];
  const int*   ei      = (const int*)d_in[1];
  const int*   batch   = (const int*)d_in[2];
  const float* W_embed = (const float*)d_in[3];
  const float* b_embed = (const float*)d_in[4];
  const float* eps     = (const float*)d_in[5];
  const float* W1[3] = {(const float*)d_in[6],  (const float*)d_in[10], (const float*)d_in[14]};
  const float* B1[3] = {(const float*)d_in[7],  (const float*)d_in[11], (const float*)d_in[15]};
  const float* W2[3] = {(const float*)d_in[8],  (const float*)d_in[12], (const float*)d_in[16]};
  const float* B2[3] = {(const float*)d_in[9],  (const float*)d_in[13], (const float*)d_in[17]};
  const float* W_task = (const float*)d_in[18];
  const float* b_task = (const float*)d_in[19];
  float* out = (float*)d_out;

  const size_t OFF_ND4 = 51200000;   // 4x100000 floats
  const size_t OFF_RZ  = 102400000;
  const size_t OFF_AUX = 153600000;
  if (ws_size < OFF_AUX + 4000000) return;
  unsigned short* RH = (unsigned short*)d_ws;
  float* nodedot4 = (float*)((char*)d_ws + OFF_ND4);
  unsigned short* RZ = (unsigned short*)((char*)d_ws + OFF_RZ);
  char* aux = (char*)d_ws + OFF_AUX;
  int* row_ptr  = (int*)(aux);               // 100001 ints
  int* cursor   = (int*)(aux + 400016);      // 100000 ints (also deg histogram)
  int* csr_src  = (int*)(aux + 800016);      // 300000 ints
  int* blk_sums = (int*)(aux + 2000016);     // 98 ints
  int* blk_off  = (int*)(aux + 2000416);     // 98 ints
  unsigned short* WT = (unsigned short*)(aux + 2400832);  // 360448 bf16
  float* w2v = (float*)(aux + 3200832);      // 512 floats
  float* c2  = (float*)(aux + 3202880);      // 1 float
  unsigned short* WfT    = WT;
  unsigned short* Wt2_0  = WT + 32768;
  unsigned short* Wt1_1  = WT + 98304;
  unsigned short* Wt2_1  = WT + 163840;
  unsigned short* Wt1_2  = WT + 229376;

  // ---- prep: all independent prologue work (1 dispatch; zeroes cursor) ----
  PrepArgs pa;
  pa.W[0] = W2[0]; pa.Wt[0] = Wt2_0; pa.K[0] = 256; pa.N[0] = 256;
  pa.W[1] = W1[1]; pa.Wt[1] = Wt1_1; pa.K[1] = 256; pa.N[1] = 256;
  pa.W[2] = W2[1]; pa.Wt[2] = Wt2_1; pa.K[2] = 256; pa.N[2] = 256;
  pa.W[3] = W1[2]; pa.Wt[3] = Wt1_2; pa.K[3] = 256; pa.N[3] = 512;
  pa.We = W_embed; pa.be = b_embed; pa.W1_0 = W1[0]; pa.WfT = WfT;
  pa.W2_2 = W2[2]; pa.b2_2 = B2[2]; pa.wtask = W_task; pa.w2v = w2v; pa.c2 = c2;
  pa.nodedot = (float*)cursor;  // zero cursor here (0.0f bits == 0)
  pa.out = out; pa.b_task = b_task;
  prep_kernel<<<889, 256, 0, stream>>>(pa);

  // ---- CSR build (zero_kernel folded into prep) ----
  hist_kernel<<<(E_EDGES + 255) / 256, 256, 0, stream>>>(ei, cursor);
  scan_blk_kernel<<<98, 256, 0, stream>>>(cursor, row_ptr, blk_sums, N_NODES, N_NODES + 1);
  scan_blk_kernel<<<1, 256, 0, stream>>>(blk_sums, blk_off, nullptr, 98, 98);
  scan_fix_kernel<<<(N_NODES + 256) / 256, 256, 0, stream>>>(row_ptr, blk_off, cursor);
  fill_kernel<<<(E_EDGES + 255) / 256, 256, 0, stream>>>(ei, cursor, csr_src);

  const int FB = (N_NODES + 63) / 64;  // 1563 fused blocks (64 rows each)

  // ---- layer 0 (folded embed): G -> H = relu(relu(G@WfT^T+b1)@W2_0+b2) ----
  gatherx_kernel<<<N_NODES / 4, 256, 0, stream>>>(x, RZ, row_ptr, csr_src, eps);
  fused_mlp_kernel<64><<<FB, 256, 0, stream>>>(RZ, WfT, B1[0], Wt2_0, B2[0], RH, N_NODES);

  // ---- layer 1 ----
  gather_kernel<<<N_NODES / 4, 256, 0, stream>>>(RH, RZ, row_ptr, csr_src, eps, 1);
  fused_mlp_kernel<256><<<FB, 256, 0, stream>>>(RZ, Wt1_1, B1[1], Wt2_1, B2[1], RH, N_NODES);

  // ---- layer 2: gather, then fused GEMM + task-dot ----
  gather_kernel<<<N_NODES / 4, 256, 0, stream>>>(RH, RZ, row_ptr, csr_src, eps, 2);
  fused_dot_kernel<<<FB, 256, 0, stream>>>(RZ, Wt1_2, B1[2], w2v, nodedot4, N_NODES);

  // ---- out[g] = b_task + sum_i (sum_w nodedot4[w][i] + c2) ----
  pool_kernel<<<(N_NODES + 255) / 256, 256, 0, stream>>>(nodedot4, batch, out, c2);
}